// Round 16
// baseline (886.570 us; speedup 1.0000x reference)
//
#include <hip/hip_runtime.h>

// ---------------------------------------------------------------------------
// Encoder: 4 layers of {LN1 -> QKVR proj -> role-gated attention -> Wo+res ->
// LN2 -> FFN(relu) + res -> LN3}.  B=4 S=1024 D=1024 H=16 DH=64 DF=4096.
// f32 I/O; internal GEMMs in fp16 MFMA (16x16x32) with f32 accumulate.
// ALL GEMMs use gemm_bt: counted-vmcnt pipeline, CH-swizzled LDS,
// NBUF=2 (double-barrier, higher occupancy: the measured lever here is
// blocks/CU TLP, not schedule depth -- 3 phase-split attempts were null).
//   QKVR/W1: <128,128,64> 64 KB LDS -> 2 blocks/CU
//   Wo/W2:   <128,64,64>  48 KB LDS -> 3 blocks/CU
// Attention: reduction-free softmax (clamped raw v_exp_f32 + ones-column
// MFMA denominator); C1 pre-folded into Q (in QKVR epilogue, z==0);
// 2-buffer KV, counted vmcnt.
// ---------------------------------------------------------------------------

typedef _Float16 f16;
typedef _Float16 f16x8 __attribute__((ext_vector_type(8)));
typedef _Float16 f16x4 __attribute__((ext_vector_type(4)));
typedef float    f32x4 __attribute__((ext_vector_type(4)));

#define GPTR(x) (const __attribute__((address_space(1))) void*)(x)
#define LPTR(x) (__attribute__((address_space(3))) void*)(x)
#define MFMA16(a,b,c) __builtin_amdgcn_mfma_f32_16x16x32_f16(a, b, c, 0, 0, 0)

static constexpr int NB   = 4;      // batch
static constexpr int NS   = 1024;   // seq
static constexpr int ND   = 1024;   // d_model
static constexpr int NH   = 16;     // heads
static constexpr int NDH  = 64;     // head dim
static constexpr int NDF  = 4096;   // ffn
static constexpr int NM   = NB * NS;        // 4096 rows
static constexpr int HD   = NH * NDH;       // 1024
static constexpr float kC1 = 0.180336879f;  // 0.125 * log2(e)

// epilogue modes
#define EPI_H      0   // outH[m*N+n] = acc + bias
#define EPI_VT     1   // outH[n*NM+m] = acc + bias   (V transposed)
#define EPI_RELU   2   // outH[m*N+n] = relu(acc + bias)
#define EPI_RESF32 3   // outF[m*N+n] = acc + bias + res[m*N+n]
#define EPI_QKVR   4   // z==2 -> VT; z==0 scaled by kC1; else EPI_H

// ---------------------------------------------------------------------------
// Weight transpose + f32->f16 convert: src (R,C) row-major f32 -> dst (C,R) f16
// ---------------------------------------------------------------------------
__global__ __launch_bounds__(256) void transpose_cvt(
    const float* __restrict__ src, f16* __restrict__ dst,
    int R, int C, int srcZ, int dstZ)
{
  src += (size_t)blockIdx.z * srcZ;
  dst += (size_t)blockIdx.z * dstZ;
  __shared__ float tile[64][65];
  int t  = threadIdx.x;
  int c0 = blockIdx.x * 64, r0 = blockIdx.y * 64;
  int tr = t >> 4, tc4 = (t & 15) * 4;
#pragma unroll
  for (int i = 0; i < 4; ++i) {
    float4 v = *(const float4*)&src[(size_t)(r0 + tr + i * 16) * C + c0 + tc4];
    tile[tr + i * 16][tc4 + 0] = v.x;
    tile[tr + i * 16][tc4 + 1] = v.y;
    tile[tr + i * 16][tc4 + 2] = v.z;
    tile[tr + i * 16][tc4 + 3] = v.w;
  }
  __syncthreads();
  int n = t >> 2, ks = (t & 3) * 16;
  f16x8 o0, o1;
#pragma unroll
  for (int j = 0; j < 8; ++j) {
    o0[j] = (f16)tile[ks + j][n];
    o1[j] = (f16)tile[ks + 8 + j][n];
  }
  f16* dp = &dst[(size_t)(c0 + n) * R + r0 + ks];
  *(f16x8*)dp       = o0;
  *(f16x8*)(dp + 8) = o1;
}

// ---------------------------------------------------------------------------
// Pack the 7 bias arrays into one contiguous buffer.
// ---------------------------------------------------------------------------
__global__ __launch_bounds__(256) void pack_bias(
    const float* __restrict__ bq, const float* __restrict__ bk,
    const float* __restrict__ bv, const float* __restrict__ br,
    const float* __restrict__ bo, const float* __restrict__ b1,
    const float* __restrict__ b2, float* __restrict__ dst)
{
  int i = blockIdx.x * 256 + threadIdx.x;
  if (i >= 4 * 10240) return;
  int l = i / 10240, o = i % 10240;
  float v;
  if      (o < 1024) v = bq[l * 1024 + o];
  else if (o < 2048) v = bk[l * 1024 + o - 1024];
  else if (o < 3072) v = bv[l * 1024 + o - 2048];
  else if (o < 4096) v = br[l * 1024 + o - 3072];
  else if (o < 5120) v = bo[l * 1024 + o - 4096];
  else if (o < 9216) v = b1[l * 4096 + o - 5120];
  else               v = b2[l * 1024 + o - 9216];
  dst[i] = v;
}

// ---------------------------------------------------------------------------
// LayerNorm over D=1024: one row per block, 256 threads x float4.
// ---------------------------------------------------------------------------
template<bool F16OUT>
__global__ __launch_bounds__(256) void ln_kernel(
    const float* __restrict__ in, const float* __restrict__ g,
    const float* __restrict__ b, void* __restrict__ out)
{
  int row = blockIdx.x, t = threadIdx.x;
  float4 v = *(const float4*)&in[(size_t)row * ND + t * 4];
  float s  = v.x + v.y + v.z + v.w;
  float sq = v.x * v.x + v.y * v.y + v.z * v.z + v.w * v.w;
#pragma unroll
  for (int off = 32; off; off >>= 1) {
    s  += __shfl_xor(s, off, 64);
    sq += __shfl_xor(sq, off, 64);
  }
  __shared__ float rb[8];
  int wid = t >> 6;
  if ((t & 63) == 0) { rb[wid] = s; rb[4 + wid] = sq; }
  __syncthreads();
  s  = rb[0] + rb[1] + rb[2] + rb[3];
  sq = rb[4] + rb[5] + rb[6] + rb[7];
  float mean = s * (1.0f / ND);
  float var  = sq * (1.0f / ND) - mean * mean;
  float rstd = rsqrtf(var + 1e-5f);
  float4 g4 = *(const float4*)&g[t * 4];
  float4 b4 = *(const float4*)&b[t * 4];
  float o0 = (v.x - mean) * rstd * g4.x + b4.x;
  float o1 = (v.y - mean) * rstd * g4.y + b4.y;
  float o2 = (v.z - mean) * rstd * g4.z + b4.z;
  float o3 = (v.w - mean) * rstd * g4.w + b4.w;
  if (F16OUT) {
    f16x4 ov = { (f16)o0, (f16)o1, (f16)o2, (f16)o3 };
    *(f16x4*)((f16*)out + (size_t)row * ND + t * 4) = ov;
  } else {
    float4 ov = { o0, o1, o2, o3 };
    *(float4*)((float*)out + (size_t)row * ND + t * 4) = ov;
  }
}

// ---------------------------------------------------------------------------
// GEMM: C(M x N) = A(M x K) * Bt(N x K)^T + bias (+ residual / relu / VT).
// Counted-vmcnt pipeline, NBUF buffers.
//  NBUF=2: {vmcnt(LPT); s_barrier; ds_read+MFMA; s_barrier; stage(cur,it+2)}
//          -- overwrite of cur is safe: all waves consumed its ds_reads
//          (register-resident) before the second barrier.
//  NBUF=3: {vmcnt(LPT); s_barrier; stage(nxt,it+2); ds_read+MFMA}.
// LDS rows chunk-XOR-swizzled (source-side pre-swizzle, both-sides rule).
// CH=8 seed row&7 (conflict-free); CH=4 seed (row>>1)&3 (2-way, free).
// f16 row-major outputs go through an LDS-staged coalesced epilogue.
// EPI_QKVR: z==2 writes V^T; z==0 (Q) scaled by kC1 for attention.
// ---------------------------------------------------------------------------
template<int BM, int BN, int BK, int NBUF>
__global__ __launch_bounds__(256) void gemm_bt(
    const f16* __restrict__ A, const f16* __restrict__ Bt,
    const float* __restrict__ bias, const float* __restrict__ res,
    f16* __restrict__ outH, float* __restrict__ outF,
    int N, int K, int epi, int zBt, int zBias, int zOut)
{
  constexpr int CH = BK / 8;
  constexpr int CM = CH - 1;
  constexpr int KH = BK / 32;
  constexpr int FM = BM / 32, FN = BN / 32;
  constexpr int ASZ = BM * BK, BSZ = BN * BK;
  constexpr int TSZ = ASZ + BSZ;
  constexpr int LPT = (BM + BN) * CH / 256;  // global_load_lds per thread/tile
  constexpr int SMEM = (NBUF * TSZ > BM * BN) ? NBUF * TSZ : BM * BN;
  __shared__ f16 sm[SMEM];

  auto SWZ = [](int row) { return ((CH == 4) ? (row >> 1) : row) & CM; };

  int nx = gridDim.x, ny = gridDim.y;
  int lin = blockIdx.x + nx * (blockIdx.y + ny * blockIdx.z);
  int tot = nx * ny * gridDim.z;
  int l2  = (lin & 7) * (tot >> 3) + (lin >> 3);
  int by  = l2 % ny; int rem = l2 / ny; int bx = rem % nx; int z = rem / nx;

  Bt += (size_t)z * zBt;
  const float* biasz = bias + (size_t)z * zBias;
  int ep = (epi == EPI_QKVR) ? ((z == 2) ? EPI_VT : EPI_H) : epi;
  bool scaleQ = (epi == EPI_QKVR) && (z == 0);

  int t = threadIdx.x;
  int wid = t >> 6, lane = t & 63;
  int wr = wid >> 1, wc = wid & 1;
  int rA = lane & 15, kg = lane >> 4;
  int m0 = bx * BM, n0 = by * BN;

  f32x4 acc[FM][FN] = {};
  const f16* Abase = A  + (size_t)m0 * K;
  const f16* Bbase = Bt + (size_t)n0 * K;

  auto stage = [&](int buf, int kt) {
    f16* As = sm + buf * TSZ;
    f16* Bs = As + ASZ;
#pragma unroll
    for (int i = 0; i < BM * CH / 256; ++i) {
      int p = i * 256 + t;
      int row = p / CH, c = (p & CM) ^ SWZ(row);
      __builtin_amdgcn_global_load_lds(
          GPTR(Abase + (size_t)row * K + kt + c * 8),
          LPTR(As + (i * 256 + wid * 64) * 8), 16, 0, 0);
    }
#pragma unroll
    for (int i = 0; i < BN * CH / 256; ++i) {
      int p = i * 256 + t;
      int row = p / CH, c = (p & CM) ^ SWZ(row);
      __builtin_amdgcn_global_load_lds(
          GPTR(Bbase + (size_t)row * K + kt + c * 8),
          LPTR(Bs + (i * 256 + wid * 64) * 8), 16, 0, 0);
    }
  };

  int nIt = K / BK;
  stage(0, 0);
  if (nIt > 1) stage(1, BK);
  int cur = 0, nxt = 2;
  for (int it = 0; it < nIt; ++it) {
    if (it + 1 < nIt) {
      asm volatile("s_waitcnt vmcnt(%0)" :: "n"(LPT) : "memory");
    } else {
      asm volatile("s_waitcnt vmcnt(0)" ::: "memory");
    }
    __builtin_amdgcn_s_barrier();
    __builtin_amdgcn_sched_barrier(0);
    if (NBUF == 2) cur = it & 1;
    if (NBUF == 3 && it + 2 < nIt) stage(nxt, (it + 2) * BK);
    const f16* As = sm + cur * TSZ;
    const f16* Bs = As + ASZ;
    f16x8 af[FM][KH], bf[FN][KH];
#pragma unroll
    for (int m = 0; m < FM; ++m) {
      int r = wr * (BM / 2) + m * 16 + rA;
#pragma unroll
      for (int h = 0; h < KH; ++h)
        af[m][h] = *(const f16x8*)&As[r * BK + (((h * 4 + kg) ^ SWZ(r)) * 8)];
    }
#pragma unroll
    for (int n = 0; n < FN; ++n) {
      int r = wc * (BN / 2) + n * 16 + rA;
#pragma unroll
      for (int h = 0; h < KH; ++h)
        bf[n][h] = *(const f16x8*)&Bs[r * BK + (((h * 4 + kg) ^ SWZ(r)) * 8)];
    }
#pragma unroll
    for (int h = 0; h < KH; ++h)
#pragma unroll
      for (int m = 0; m < FM; ++m)
#pragma unroll
        for (int n = 0; n < FN; ++n)
          acc[m][n] = MFMA16(af[m][h], bf[n][h], acc[m][n]);
    if (NBUF == 2) {
      if (it + 2 < nIt) {
        __builtin_amdgcn_sched_barrier(0);
        __builtin_amdgcn_s_barrier();   // all waves done reading buf cur
        stage(cur, (it + 2) * BK);      // overwrite; lands in ~1 full iter
      }
    } else {
      cur = (cur == 2) ? 0 : cur + 1;
      nxt = (nxt == 2) ? 0 : nxt + 1;
    }
  }

  // ---- epilogue (fragment: C row = kg*4 + r, col = rA) -------------------
  if (ep == EPI_H || ep == EPI_RELU) {
    __builtin_amdgcn_sched_barrier(0);
    __builtin_amdgcn_s_barrier();
#pragma unroll
    for (int n = 0; n < FN; ++n) {
      int cl = wc * (BN / 2) + n * 16 + rA;
      float bvv = biasz[n0 + cl];
#pragma unroll
      for (int m = 0; m < FM; ++m) {
        int rl = wr * (BM / 2) + m * 16 + kg * 4;
#pragma unroll
        for (int r = 0; r < 4; ++r) {
          float v = acc[m][n][r] + bvv;
          if (ep == EPI_RELU) v = fmaxf(v, 0.0f);
          if (scaleQ) v *= kC1;
          sm[(rl + r) * BN + cl] = (f16)v;
        }
      }
    }
    __syncthreads();
    f16* outp = outH + (size_t)z * zOut;
#pragma unroll
    for (int i = 0; i < BM * BN / 2048; ++i) {
      int p = i * 256 + t;
      int row = p / (BN / 8), c8 = p % (BN / 8);
      *(f16x8*)&outp[(size_t)(m0 + row) * N + n0 + c8 * 8] =
          *(const f16x8*)&sm[row * BN + c8 * 8];
    }
  } else {
#pragma unroll
    for (int n = 0; n < FN; ++n) {
      int gn = n0 + wc * (BN / 2) + n * 16 + rA;
      float bvv = biasz[gn];
#pragma unroll
      for (int m = 0; m < FM; ++m) {
        int gmb = m0 + wr * (BM / 2) + m * 16 + kg * 4;
        if (ep == EPI_VT) {
          f16x4 ov = { (f16)(acc[m][n][0] + bvv), (f16)(acc[m][n][1] + bvv),
                       (f16)(acc[m][n][2] + bvv), (f16)(acc[m][n][3] + bvv) };
          *(f16x4*)&outH[(size_t)z * zOut + (size_t)gn * NM + gmb] = ov;
        } else {
#pragma unroll
          for (int r = 0; r < 4; ++r) {
            int gm = gmb + r;
            outF[(size_t)gm * N + gn] =
                acc[m][n][r] + bvv + res[(size_t)gm * N + gn];
          }
        }
      }
    }
  }
}

// ---------------------------------------------------------------------------
// Role-gated flash attention.  grid 512, 256 threads = 4 waves, 32 q/wave.
// 2-buffer KV (48 KB LDS -> 3 blocks/CU), double-barrier counted-vmcnt.
// Softmax reduction-free: Q pre-scaled by kC1, P = v_exp_f32(min(sc,14.5));
// denominator = P @ ones via MFMA.
// ---------------------------------------------------------------------------
__global__ __launch_bounds__(256) void attn_kernel(
    const f16* __restrict__ Qm, const f16* __restrict__ Km,
    const f16* __restrict__ Vt, const f16* __restrict__ Rm,
    f16* __restrict__ outA)
{
  int t = threadIdx.x, wid = t >> 6, lane = t & 63;
  int rA = lane & 15, kg = lane >> 4;
  int id = blockIdx.x;
  int j = id >> 3;
  int bh = (id & 7) * 8 + (j & 7), qb = j >> 3;   // XCD-contiguous per head
  int b = bh >> 4, h = bh & 15;
  int q0 = qb * 128 + wid * 32;

  __shared__ f16 KVs[2][2 * 64 * 64];   // 32 KB
  __shared__ f16 P[4][32 * 64];         // 16 KB
  f16* Pw = P[wid];

  f16x8 aq[2][2];
#pragma unroll
  for (int mf = 0; mf < 2; ++mf) {
    size_t qoff = (size_t)(b * NS + q0 + mf * 16 + rA) * HD + h * NDH + kg * 8;
    aq[mf][0] = *(const f16x8*)&Qm[qoff];
    aq[mf][1] = *(const f16x8*)&Qm[qoff + 32];
  }

  f32x4 o[2][4] = {};
  f32x4 osum[2] = {};
  f16x8 vones;
#pragma unroll
  for (int jj = 0; jj < 8; ++jj) vones[jj] = (f16)1.0f;

  auto stage = [&](int buf, int kv) {
    f16* Ks = KVs[buf];
    f16* Vs = Ks + 64 * 64;
#pragma unroll
    for (int i = 0; i < 2; ++i) {
      int p = i * 256 + t;
      int row = p >> 3, c16 = (p & 7) ^ (row & 7);
      __builtin_amdgcn_global_load_lds(
          GPTR(Km + (size_t)(b * NS + kv + row) * HD + h * NDH + c16 * 8),
          LPTR(Ks + (i * 256 + wid * 64) * 8), 16, 0, 0);
    }
#pragma unroll
    for (int i = 0; i < 2; ++i) {
      int p = i * 256 + t;
      int row = p >> 3, c16 = (p & 7) ^ (row & 7);
      __builtin_amdgcn_global_load_lds(
          GPTR(Vt + (size_t)(h * NDH + row) * NM + b * NS + kv + c16 * 8),
          LPTR(Vs + (i * 256 + wid * 64) * 8), 16, 0, 0);
    }
  };

  stage(0, 0);
  stage(1, 64);
  for (int tt = 0; tt < NS / 64; ++tt) {
    int cur = tt & 1;
    if (tt + 1 < NS / 64) {
      asm volatile("s_waitcnt vmcnt(4)" ::: "memory");
    } else {
      asm volatile("s_waitcnt vmcnt(0)" ::: "memory");
    }
    __builtin_amdgcn_s_barrier();
    __builtin_amdgcn_sched_barrier(0);
    const f16* Kc = KVs[cur];
    const f16* Vc = Kc + 64 * 64;

    f32x4 sc[2][4];
#pragma unroll
    for (int ct = 0; ct < 4; ++ct) {
      int krow = ct * 16 + rA;
      f16x8 kb0 = *(const f16x8*)&Kc[krow * 64 + ((kg ^ (rA & 7)) * 8)];
      f16x8 kb1 = *(const f16x8*)&Kc[krow * 64 + (((4 + kg) ^ (rA & 7)) * 8)];
#pragma unroll
      for (int mf = 0; mf < 2; ++mf) {
        f32x4 a = {};
        a = MFMA16(aq[mf][0], kb0, a);
        a = MFMA16(aq[mf][1], kb1, a);
        sc[mf][ct] = a;
      }
    }

#pragma unroll
    for (int mf = 0; mf < 2; ++mf)
#pragma unroll
      for (int ct = 0; ct < 4; ++ct)
#pragma unroll
        for (int r = 0; r < 4; ++r) {
          float arg = fminf(sc[mf][ct][r], 14.5f);
          float p;
          asm("v_exp_f32 %0, %1" : "=v"(p) : "v"(arg));
          Pw[(mf * 16 + kg * 4 + r) * 64 + ((ct ^ kg) * 16 + rA)] = (f16)p;
        }

#pragma unroll
    for (int kc = 0; kc < 2; ++kc) {
      f16x8 vb[4];
#pragma unroll
      for (int dt = 0; dt < 4; ++dt)
        vb[dt] = *(const f16x8*)&Vc[(dt * 16 + rA) * 64 + (((kc * 4 + kg) ^ (rA & 7)) * 8)];
#pragma unroll
      for (int mf = 0; mf < 2; ++mf) {
        f16x8 pa = *(const f16x8*)&Pw[(mf * 16 + rA) * 64 + ((kc * 32 + kg * 8) ^ ((rA >> 2) << 4))];
#pragma unroll
        for (int dt = 0; dt < 4; ++dt)
          o[mf][dt] = MFMA16(pa, vb[dt], o[mf][dt]);
        osum[mf] = MFMA16(pa, vones, osum[mf]);
      }
    }
    if (tt + 2 < NS / 64) {
      __builtin_amdgcn_sched_barrier(0);
      __builtin_amdgcn_s_barrier();
      stage(cur, (tt + 2) * 64);
    }
  }

  float lrinv[2][4];
#pragma unroll
  for (int mf = 0; mf < 2; ++mf)
#pragma unroll
    for (int r = 0; r < 4; ++r) lrinv[mf][r] = 1.0f / osum[mf][r];
#pragma unroll
  for (int mf = 0; mf < 2; ++mf)
#pragma unroll
    for (int dt = 0; dt < 4; ++dt)
#pragma unroll
      for (int r = 0; r < 4; ++r) {
        size_t idx = (size_t)(b * NS + q0 + mf * 16 + kg * 4 + r) * HD + h * NDH + dt * 16 + rA;
        float v = o[mf][dt][r] * lrinv[mf][r] * (float)Rm[idx];
        outA[idx] = (f16)v;
      }
}

// ---------------------------------------------------------------------------
// Host launcher
// ---------------------------------------------------------------------------
extern "C" void kernel_launch(void* const* d_in, const int* in_sizes, int n_in,
                              void* d_out, int out_size, void* d_ws, size_t ws_size,
                              hipStream_t stream)
{
  const float* src  = (const float*)d_in[0];
  const float* ln1g = (const float*)d_in[2];
  const float* ln1b = (const float*)d_in[3];
  const float* Wq   = (const float*)d_in[4];
  const float* bq   = (const float*)d_in[5];
  const float* Wk   = (const float*)d_in[6];
  const float* bk   = (const float*)d_in[7];
  const float* Wv   = (const float*)d_in[8];
  const float* bv   = (const float*)d_in[9];
  const float* Wr   = (const float*)d_in[10];
  const float* br   = (const float*)d_in[11];
  const float* Wo   = (const float*)d_in[12];
  const float* bo   = (const float*)d_in[13];
  const float* ln2g = (const float*)d_in[14];
  const float* ln2b = (const float*)d_in[15];
  const float* W1   = (const float*)d_in[16];
  const float* b1   = (const float*)d_in[17];
  const float* W2   = (const float*)d_in[18];
  const float* b2   = (const float*)d_in[19];
  const float* ln3g = (const float*)d_in[20];
  const float* ln3b = (const float*)d_in[21];

  // ---- workspace layout -------------------------------------------------
  char* ws = (char*)d_ws;
  float* biasbuf = (float*)ws;
  size_t off = 40960 * sizeof(float);
  const size_t WT_L = 13631488;  // f16 elements per layer: 5*1M + 4M + 4M
  size_t act_bytes = (size_t)NM * 1024 * 20;
  bool upfront = ws_size >= off + 4 * WT_L * 2 + act_bytes;
  f16* wt = (f16*)(ws + off);
  off += (upfront ? 4 : 1) * WT_L * 2;
  float* xbuf = (float*)(ws + off); off += (size_t)NM * ND * 4;
  float* mha  = (float*)(ws + off); off += (size_t)NM * ND * 4;
  f16* zbuf   = (f16*)(ws + off);   off += (size_t)NM * ND * 2;
  f16* qkvr   = (f16*)(ws + off);   off += (size_t)NM * ND * 2 * 4;  // also h1
  f16* aout   = (f16*)(ws + off);

  pack_bias<<<160, 256, 0, stream>>>(bq, bk, bv, br, bo, b1, b2, biasbuf);

  if (upfront) {
    transpose_cvt<<<dim3(16, 16, 4), 256, 0, stream>>>(Wq, wt + 0,       1024, 1024, 1048576, (int)WT_L);
    transpose_cvt<<<dim3(16, 16, 4), 256, 0, stream>>>(Wk, wt + 1048576, 1024, 1024, 1048576, (int)WT_L);
    transpose_cvt<<<dim3(16, 16, 4), 256, 0, stream>>>(Wv, wt + 2097152, 1024, 1024, 1048576, (int)WT_L);
    transpose_cvt<<<dim3(16, 16, 4), 256, 0, stream>>>(Wr, wt + 3145728, 1024, 1024, 1048576, (int)WT_L);
    transpose_cvt<<<dim3(16, 16, 4), 256, 0, stream>>>(Wo, wt + 4194304, 1024, 1024, 1048576, (int)WT_L);
    transpose_cvt<<<dim3(64, 16, 4), 256, 0, stream>>>(W1, wt + 5242880, 1024, 4096, 4194304, (int)WT_L);
    transpose_cvt<<<dim3(16, 64, 4), 256, 0, stream>>>(W2, wt + 9437184, 4096, 1024, 4194304, (int)WT_L);
  }

  for (int l = 0; l < 4; ++l) {
    f16* wtL = upfront ? wt + (size_t)l * WT_L : wt;
    const float* bL = biasbuf + l * 10240;
    if (!upfront) {
      transpose_cvt<<<dim3(16, 16, 1), 256, 0, stream>>>(Wq + (size_t)l * 1048576, wt + 0,       1024, 1024, 0, 0);
      transpose_cvt<<<dim3(16, 16, 1), 256, 0, stream>>>(Wk + (size_t)l * 1048576, wt + 1048576, 1024, 1024, 0, 0);
      transpose_cvt<<<dim3(16, 16, 1), 256, 0, stream>>>(Wv + (size_t)l * 1048576, wt + 2097152, 1024, 1024, 0, 0);
      transpose_cvt<<<dim3(16, 16, 1), 256, 0, stream>>>(Wr + (size_t)l * 1048576, wt + 3145728, 1024, 1024, 0, 0);
      transpose_cvt<<<dim3(16, 16, 1), 256, 0, stream>>>(Wo + (size_t)l * 1048576, wt + 4194304, 1024, 1024, 0, 0);
      transpose_cvt<<<dim3(64, 16, 1), 256, 0, stream>>>(W1 + (size_t)l * 4194304, wt + 5242880, 1024, 4096, 0, 0);
      transpose_cvt<<<dim3(16, 64, 1), 256, 0, stream>>>(W2 + (size_t)l * 4194304, wt + 9437184, 4096, 1024, 0, 0);
    }
    const float* xin = l ? xbuf : src;

    // z = LN1(x)
    ln_kernel<true><<<NM, 256, 0, stream>>>(xin, ln1g + l * 1024, ln1b + l * 1024, zbuf);
    // Q,K,Vt,R = z @ {Wq,Wk,Wv,Wr} + b  (Q scaled by kC1; V written transposed)
    gemm_bt<128, 128, 64, 2><<<dim3(32, 8, 4), 256, 0, stream>>>(
        zbuf, wtL, bL, nullptr, qkvr, nullptr, 1024, 1024, EPI_QKVR, 1048576, 1024, 4194304);
    // gated attention -> aout (f16)
    attn_kernel<<<dim3(512), 256, 0, stream>>>(
        qkvr, qkvr + 4194304, qkvr + 8388608, qkvr + 12582912, aout);
    // mha = x + aout @ Wo + bo
    gemm_bt<128, 64, 64, 2><<<dim3(32, 16, 1), 256, 0, stream>>>(
        aout, wtL + 4194304, bL + 4096, xin, nullptr, mha, 1024, 1024, EPI_RESF32, 0, 0, 0);
    // z2 = LN2(mha)
    ln_kernel<true><<<NM, 256, 0, stream>>>(mha, ln2g + l * 1024, ln2b + l * 1024, zbuf);
    // h1 = relu(z2 @ W1 + b1)   (reuses QKVR buffer, N=4096)
    gemm_bt<128, 128, 64, 2><<<dim3(32, 32, 1), 256, 0, stream>>>(
        zbuf, wtL + 5242880, bL + 5120, nullptr, qkvr, nullptr, 4096, 1024, EPI_RELU, 0, 0, 0);
    // mha = mha + h1 @ W2 + b2   (in-place residual)
    gemm_bt<128, 64, 64, 2><<<dim3(32, 16, 1), 256, 0, stream>>>(
        qkvr, wtL + 9437184, bL + 9216, mha, nullptr, mha, 1024, 4096, EPI_RESF32, 0, 0, 0);
    // x_next = LN3(mha)   (last layer -> d_out, f32)
    float* lnout = (l == 3) ? (float*)d_out : xbuf;
    ln_kernel<false><<<NM, 256, 0, stream>>>(mha, ln3g + l * 1024, ln3b + l * 1024, lnout);
  }
}

// Round 17
// 856.954 us; speedup vs baseline: 1.0346x; 1.0346x over previous
//
#include <hip/hip_runtime.h>

// ---------------------------------------------------------------------------
// Encoder: 4 layers of {LN1 -> QKVR proj -> role-gated attention -> Wo+res ->
// LN2 -> FFN(relu) + res -> LN3}.  B=4 S=1024 D=1024 H=16 DH=64 DF=4096.
// f32 I/O; internal GEMMs in fp16 MFMA (16x16x32) with f32 accumulate.
// N=4096 GEMMs (QKVR-unified, W1): 256x256xBK64 8-wave kernel, 2-buffer
// counted-vmcnt pipeline, K-tile split into 4 quadrant phases
// (lgkmcnt(0) + setprio around each 16-MFMA cluster; stage in phase 3).
// N=1024 K-large GEMMs (Wo, W2): 128x64xBK64 3-buffer pipeline.
// Attention: reduction-free softmax (clamped raw v_exp_f32 + ones-column
// MFMA denominator); C1 pre-folded into Q; 2-buffer KV, counted vmcnt.
// [R16: reverted to the best-measured configuration (855.6 us).]
// ---------------------------------------------------------------------------

typedef _Float16 f16;
typedef _Float16 f16x8 __attribute__((ext_vector_type(8)));
typedef _Float16 f16x4 __attribute__((ext_vector_type(4)));
typedef float    f32x4 __attribute__((ext_vector_type(4)));

#define GPTR(x) (const __attribute__((address_space(1))) void*)(x)
#define LPTR(x) (__attribute__((address_space(3))) void*)(x)
#define MFMA16(a,b,c) __builtin_amdgcn_mfma_f32_16x16x32_f16(a, b, c, 0, 0, 0)

static constexpr int NB   = 4;      // batch
static constexpr int NS   = 1024;   // seq
static constexpr int ND   = 1024;   // d_model
static constexpr int NH   = 16;     // heads
static constexpr int NDH  = 64;     // head dim
static constexpr int NDF  = 4096;   // ffn
static constexpr int NM   = NB * NS;        // 4096 rows
static constexpr int HD   = NH * NDH;       // 1024
static constexpr float kC1 = 0.180336879f;  // 0.125 * log2(e)

// epilogue modes
#define EPI_H      0   // outH[m*N+n] = acc + bias
#define EPI_VT     1   // outH[n*NM+m] = acc + bias   (V transposed for attention)
#define EPI_RELU   2   // outH[m*N+n] = relu(acc + bias)
#define EPI_RESF32 3   // outF[m*N+n] = acc + bias + res[m*N+n]
#define EPI_QKVR   4   // z==2 -> EPI_VT else EPI_H; z==0 scaled by kC1

// ---------------------------------------------------------------------------
// Weight transpose + f32->f16 convert: src (R,C) row-major f32 -> dst (C,R) f16
// grid (C/64, R/64, z), 256 threads
// ---------------------------------------------------------------------------
__global__ __launch_bounds__(256) void transpose_cvt(
    const float* __restrict__ src, f16* __restrict__ dst,
    int R, int C, int srcZ, int dstZ)
{
  src += (size_t)blockIdx.z * srcZ;
  dst += (size_t)blockIdx.z * dstZ;
  __shared__ float tile[64][65];
  int t  = threadIdx.x;
  int c0 = blockIdx.x * 64, r0 = blockIdx.y * 64;
  int tr = t >> 4, tc4 = (t & 15) * 4;
#pragma unroll
  for (int i = 0; i < 4; ++i) {
    float4 v = *(const float4*)&src[(size_t)(r0 + tr + i * 16) * C + c0 + tc4];
    tile[tr + i * 16][tc4 + 0] = v.x;
    tile[tr + i * 16][tc4 + 1] = v.y;
    tile[tr + i * 16][tc4 + 2] = v.z;
    tile[tr + i * 16][tc4 + 3] = v.w;
  }
  __syncthreads();
  int n = t >> 2, ks = (t & 3) * 16;
  f16x8 o0, o1;
#pragma unroll
  for (int j = 0; j < 8; ++j) {
    o0[j] = (f16)tile[ks + j][n];
    o1[j] = (f16)tile[ks + 8 + j][n];
  }
  f16* dp = &dst[(size_t)(c0 + n) * R + r0 + ks];
  *(f16x8*)dp       = o0;
  *(f16x8*)(dp + 8) = o1;
}

// ---------------------------------------------------------------------------
// Pack the 7 bias arrays into one contiguous buffer:
// per layer: [bq bk bv br bo](5*1024) [b1](4096) [b2](1024) = 10240 floats
// ---------------------------------------------------------------------------
__global__ __launch_bounds__(256) void pack_bias(
    const float* __restrict__ bq, const float* __restrict__ bk,
    const float* __restrict__ bv, const float* __restrict__ br,
    const float* __restrict__ bo, const float* __restrict__ b1,
    const float* __restrict__ b2, float* __restrict__ dst)
{
  int i = blockIdx.x * 256 + threadIdx.x;
  if (i >= 4 * 10240) return;
  int l = i / 10240, o = i % 10240;
  float v;
  if      (o < 1024) v = bq[l * 1024 + o];
  else if (o < 2048) v = bk[l * 1024 + o - 1024];
  else if (o < 3072) v = bv[l * 1024 + o - 2048];
  else if (o < 4096) v = br[l * 1024 + o - 3072];
  else if (o < 5120) v = bo[l * 1024 + o - 4096];
  else if (o < 9216) v = b1[l * 4096 + o - 5120];
  else               v = b2[l * 1024 + o - 9216];
  dst[i] = v;
}

// ---------------------------------------------------------------------------
// LayerNorm over D=1024: one row per block, 256 threads x float4.
// ---------------------------------------------------------------------------
template<bool F16OUT>
__global__ __launch_bounds__(256) void ln_kernel(
    const float* __restrict__ in, const float* __restrict__ g,
    const float* __restrict__ b, void* __restrict__ out)
{
  int row = blockIdx.x, t = threadIdx.x;
  float4 v = *(const float4*)&in[(size_t)row * ND + t * 4];
  float s  = v.x + v.y + v.z + v.w;
  float sq = v.x * v.x + v.y * v.y + v.z * v.z + v.w * v.w;
#pragma unroll
  for (int off = 32; off; off >>= 1) {
    s  += __shfl_xor(s, off, 64);
    sq += __shfl_xor(sq, off, 64);
  }
  __shared__ float rb[8];
  int wid = t >> 6;
  if ((t & 63) == 0) { rb[wid] = s; rb[4 + wid] = sq; }
  __syncthreads();
  s  = rb[0] + rb[1] + rb[2] + rb[3];
  sq = rb[4] + rb[5] + rb[6] + rb[7];
  float mean = s * (1.0f / ND);
  float var  = sq * (1.0f / ND) - mean * mean;
  float rstd = rsqrtf(var + 1e-5f);
  float4 g4 = *(const float4*)&g[t * 4];
  float4 b4 = *(const float4*)&b[t * 4];
  float o0 = (v.x - mean) * rstd * g4.x + b4.x;
  float o1 = (v.y - mean) * rstd * g4.y + b4.y;
  float o2 = (v.z - mean) * rstd * g4.z + b4.z;
  float o3 = (v.w - mean) * rstd * g4.w + b4.w;
  if (F16OUT) {
    f16x4 ov = { (f16)o0, (f16)o1, (f16)o2, (f16)o3 };
    *(f16x4*)((f16*)out + (size_t)row * ND + t * 4) = ov;
  } else {
    float4 ov = { o0, o1, o2, o3 };
    *(float4*)((float*)out + (size_t)row * ND + t * 4) = ov;
  }
}

// ---------------------------------------------------------------------------
// gemm256: C(4096 x 4096) = A(4096 x K) * Bt(4096 x K)^T + bias, f16 out.
// 256x256xBK64 tile, 512 threads = 8 waves (2 wave-rows x 4 wave-cols),
// per-wave output 128x64 = acc[8][4]; 64 MFMA/wave per K-tile.
// K-tile split into 4 quadrant phases (mh,nh), 16 MFMA each:
//   phase0 (m0-3,n0-1): ds_read af[0..3]+bf[0..1]; phase1 (m0-3,n2-3):
//   ds_read bf[2..3]; phase2 (m4-7,n0-1): ds_read af[4..7];
//   phase3 (m4-7,n2-3): no reads -> issue stage(it+2 -> cur) here (buf cur
//   is register-resident for all waves after phase2's barrier).
// Each phase: lgkmcnt(0)+sched_barrier, setprio(1) MFMA setprio(0), barrier.
// Iter top: vmcnt(8) + barrier.  LDS 128 KB, CH=8 swizzle (conflict-free).
// EPI_QKVR: z = n0>>10; z==2 writes V^T; z==0 (Q) scaled by kC1 for attn.
// ---------------------------------------------------------------------------
template<int EPIMODE>
__global__ __launch_bounds__(512, 2) void gemm256(
    const f16* __restrict__ A, const f16* __restrict__ Bt,
    const float* __restrict__ bias, f16* __restrict__ outH, int K)
{
  constexpr int BM = 256, BN = 256, BK = 64;
  constexpr int ASZ = BM * BK;         // 16384 f16
  constexpr int TSZ = 2 * ASZ;         // A+B per buffer = 32768 f16 (64 KB)
  __shared__ f16 sm[2 * TSZ];          // 128 KB; epilogue reuses as [256][256]

  // XCD-chunked mapping, by-fastest: 256 blocks, chunk = 2 bx x all 16 by.
  int lin = blockIdx.x + (blockIdx.y << 4);
  int l2  = (lin & 7) * 32 + (lin >> 3);
  int by  = l2 & 15, bx = l2 >> 4;

  int t = threadIdx.x;
  int wid = t >> 6, lane = t & 63;
  int wr = wid >> 2, wc = wid & 3;
  int rA = lane & 15, kg = lane >> 4;
  int m0 = bx * BM, n0 = by * BN;

  f32x4 acc[8][4] = {};
  const f16* Abase = A  + (size_t)m0 * K;
  const f16* Bbase = Bt + (size_t)n0 * K;

  auto stage = [&](int buf, int kt) {
    f16* As = sm + buf * TSZ;
    f16* Bs = As + ASZ;
#pragma unroll
    for (int i = 0; i < 4; ++i) {
      int p = i * 512 + t;
      int row = p >> 3, c = (p & 7) ^ (row & 7);
      __builtin_amdgcn_global_load_lds(
          GPTR(Abase + (size_t)row * K + kt + c * 8),
          LPTR(As + (i * 512 + wid * 64) * 8), 16, 0, 0);
    }
#pragma unroll
    for (int i = 0; i < 4; ++i) {
      int p = i * 512 + t;
      int row = p >> 3, c = (p & 7) ^ (row & 7);
      __builtin_amdgcn_global_load_lds(
          GPTR(Bbase + (size_t)row * K + kt + c * 8),
          LPTR(Bs + (i * 512 + wid * 64) * 8), 16, 0, 0);
    }
  };

  int nIt = K / BK;                    // 16
  stage(0, 0);
  stage(1, BK);
  for (int it = 0; it < nIt; ++it) {
    int cur = it & 1;
    if (it + 1 < nIt) {
      asm volatile("s_waitcnt vmcnt(8)" ::: "memory");
    } else {
      asm volatile("s_waitcnt vmcnt(0)" ::: "memory");
    }
    __builtin_amdgcn_s_barrier();
    __builtin_amdgcn_sched_barrier(0);
    const f16* As = sm + cur * TSZ;
    const f16* Bs = As + ASZ;
    f16x8 af[8][2], bf[4][2];

    // ---- phase 0: (m0-3, n0-1); reads af[0..3], bf[0..1] ----------------
#pragma unroll
    for (int m = 0; m < 4; ++m) {
      int r = wr * 128 + m * 16 + rA;
#pragma unroll
      for (int h = 0; h < 2; ++h)
        af[m][h] = *(const f16x8*)&As[r * BK + (((h * 4 + kg) ^ (r & 7)) * 8)];
    }
#pragma unroll
    for (int n = 0; n < 2; ++n) {
      int r = wc * 64 + n * 16 + rA;
#pragma unroll
      for (int h = 0; h < 2; ++h)
        bf[n][h] = *(const f16x8*)&Bs[r * BK + (((h * 4 + kg) ^ (r & 7)) * 8)];
    }
    asm volatile("s_waitcnt lgkmcnt(0)" ::: "memory");
    __builtin_amdgcn_sched_barrier(0);
    __builtin_amdgcn_s_setprio(1);
#pragma unroll
    for (int h = 0; h < 2; ++h)
#pragma unroll
      for (int m = 0; m < 4; ++m)
#pragma unroll
        for (int n = 0; n < 2; ++n)
          acc[m][n] = MFMA16(af[m][h], bf[n][h], acc[m][n]);
    __builtin_amdgcn_s_setprio(0);
    __builtin_amdgcn_sched_barrier(0);
    __builtin_amdgcn_s_barrier();

    // ---- phase 1: (m0-3, n2-3); reads bf[2..3] --------------------------
#pragma unroll
    for (int n = 2; n < 4; ++n) {
      int r = wc * 64 + n * 16 + rA;
#pragma unroll
      for (int h = 0; h < 2; ++h)
        bf[n][h] = *(const f16x8*)&Bs[r * BK + (((h * 4 + kg) ^ (r & 7)) * 8)];
    }
    asm volatile("s_waitcnt lgkmcnt(0)" ::: "memory");
    __builtin_amdgcn_sched_barrier(0);
    __builtin_amdgcn_s_setprio(1);
#pragma unroll
    for (int h = 0; h < 2; ++h)
#pragma unroll
      for (int m = 0; m < 4; ++m)
#pragma unroll
        for (int n = 2; n < 4; ++n)
          acc[m][n] = MFMA16(af[m][h], bf[n][h], acc[m][n]);
    __builtin_amdgcn_s_setprio(0);
    __builtin_amdgcn_sched_barrier(0);
    __builtin_amdgcn_s_barrier();

    // ---- phase 2: (m4-7, n0-1); reads af[4..7] --------------------------
#pragma unroll
    for (int m = 4; m < 8; ++m) {
      int r = wr * 128 + m * 16 + rA;
#pragma unroll
      for (int h = 0; h < 2; ++h)
        af[m][h] = *(const f16x8*)&As[r * BK + (((h * 4 + kg) ^ (r & 7)) * 8)];
    }
    asm volatile("s_waitcnt lgkmcnt(0)" ::: "memory");
    __builtin_amdgcn_sched_barrier(0);
    __builtin_amdgcn_s_setprio(1);
#pragma unroll
    for (int h = 0; h < 2; ++h)
#pragma unroll
      for (int m = 4; m < 8; ++m)
#pragma unroll
        for (int n = 0; n < 2; ++n)
          acc[m][n] = MFMA16(af[m][h], bf[n][h], acc[m][n]);
    __builtin_amdgcn_s_setprio(0);
    __builtin_amdgcn_sched_barrier(0);
    __builtin_amdgcn_s_barrier();

    // ---- phase 3: (m4-7, n2-3); no reads -> issue next-next stage -------
    // buf cur is dead in LDS for ALL waves after phase2's barrier (every
    // fragment is register-resident), so overwriting it is race-free.
    if (it + 2 < nIt) stage(cur, (it + 2) * BK);
    __builtin_amdgcn_s_setprio(1);
#pragma unroll
    for (int h = 0; h < 2; ++h)
#pragma unroll
      for (int m = 4; m < 8; ++m)
#pragma unroll
        for (int n = 2; n < 4; ++n)
          acc[m][n] = MFMA16(af[m][h], bf[n][h], acc[m][n]);
    __builtin_amdgcn_s_setprio(0);
    __builtin_amdgcn_sched_barrier(0);
  }

  // ---- epilogue (fragment: C row = kg*4 + r, col = rA) -------------------
  __builtin_amdgcn_s_barrier();        // staging buffers now dead -> reuse sm
  if (EPIMODE == EPI_QKVR && (n0 >> 10) == 2) {
    // V^T: direct f16x4 stores along gm
    f16* vt = outH + (size_t)2 * 4194304;
#pragma unroll
    for (int n = 0; n < 4; ++n) {
      int gn = n0 + wc * 64 + n * 16 + rA;
      int gnl = gn & 1023;
      float bvv = bias[gn];
#pragma unroll
      for (int m = 0; m < 8; ++m) {
        int gmb = m0 + wr * 128 + m * 16 + kg * 4;
        f16x4 ov = { (f16)(acc[m][n][0] + bvv), (f16)(acc[m][n][1] + bvv),
                     (f16)(acc[m][n][2] + bvv), (f16)(acc[m][n][3] + bvv) };
        *(f16x4*)&vt[(size_t)gnl * NM + gmb] = ov;
      }
    }
  } else {
    // LDS-staged coalesced store of the [256][256] tile
    bool scaleQ = (EPIMODE == EPI_QKVR) && ((n0 >> 10) == 0);
#pragma unroll
    for (int n = 0; n < 4; ++n) {
      int cl = wc * 64 + n * 16 + rA;
      float bvv = bias[n0 + cl];
#pragma unroll
      for (int m = 0; m < 8; ++m) {
        int rl = wr * 128 + m * 16 + kg * 4;
#pragma unroll
        for (int r = 0; r < 4; ++r) {
          float v = acc[m][n][r] + bvv;
          if (EPIMODE == EPI_RELU) v = fmaxf(v, 0.0f);
          if (scaleQ) v *= kC1;
          sm[(rl + r) * 256 + cl] = (f16)v;
        }
      }
    }
    __syncthreads();
    f16* outp;
    int ldo, col0;
    if (EPIMODE == EPI_QKVR) {
      int z = n0 >> 10;
      outp = outH + (size_t)z * 4194304; ldo = 1024; col0 = n0 & 1023;
    } else {
      outp = outH; ldo = 4096; col0 = n0;
    }
#pragma unroll
    for (int i = 0; i < 16; ++i) {
      int p = i * 512 + t;
      int row = p >> 5, c8 = p & 31;
      *(f16x8*)&outp[(size_t)(m0 + row) * ldo + col0 + c8 * 8] =
          *(const f16x8*)&sm[row * 256 + c8 * 8];
    }
  }
}

// ---------------------------------------------------------------------------
// GEMM: C(M x N) = A(M x K) * Bt(N x K)^T + bias (+ residual / relu / VT).
// 3-buffer counted-vmcnt pipeline.  Used for Wo, W2.
// ---------------------------------------------------------------------------
template<int BM, int BN, int BK>
__global__ __launch_bounds__(256) void gemm_bt(
    const f16* __restrict__ A, const f16* __restrict__ Bt,
    const float* __restrict__ bias, const float* __restrict__ res,
    f16* __restrict__ outH, float* __restrict__ outF,
    int N, int K, int epi, int zBt, int zBias, int zOut)
{
  constexpr int CH = BK / 8;       // 16B chunks per LDS row
  constexpr int CM = CH - 1;
  constexpr int KH = BK / 32;      // MFMA k-steps per tile
  constexpr int FM = BM / 32, FN = BN / 32;
  constexpr int ASZ = BM * BK, BSZ = BN * BK;
  constexpr int TSZ = ASZ + BSZ;
  constexpr int LPT = (BM + BN) * CH / 256;  // global_load_lds per thread/tile
  constexpr int SMEM = (3 * TSZ > BM * BN) ? 3 * TSZ : BM * BN;
  __shared__ f16 sm[SMEM];

  auto SWZ = [](int row) { return ((CH == 4) ? (row >> 1) : row) & CM; };

  int nx = gridDim.x, ny = gridDim.y;
  int lin = blockIdx.x + nx * (blockIdx.y + ny * blockIdx.z);
  int tot = nx * ny * gridDim.z;
  int l2  = (lin & 7) * (tot >> 3) + (lin >> 3);
  int by  = l2 % ny; int rem = l2 / ny; int bx = rem % nx; int z = rem / nx;

  Bt += (size_t)z * zBt;
  const float* biasz = bias + (size_t)z * zBias;
  int ep = (epi == EPI_QKVR) ? ((z == 2) ? EPI_VT : EPI_H) : epi;

  int t = threadIdx.x;
  int wid = t >> 6, lane = t & 63;
  int wr = wid >> 1, wc = wid & 1;
  int rA = lane & 15, kg = lane >> 4;
  int m0 = bx * BM, n0 = by * BN;

  f32x4 acc[FM][FN] = {};
  const f16* Abase = A  + (size_t)m0 * K;
  const f16* Bbase = Bt + (size_t)n0 * K;

  auto stage = [&](int buf, int kt) {
    f16* As = sm + buf * TSZ;
    f16* Bs = As + ASZ;
#pragma unroll
    for (int i = 0; i < BM * CH / 256; ++i) {
      int p = i * 256 + t;
      int row = p / CH, c = (p & CM) ^ SWZ(row);
      __builtin_amdgcn_global_load_lds(
          GPTR(Abase + (size_t)row * K + kt + c * 8),
          LPTR(As + (i * 256 + wid * 64) * 8), 16, 0, 0);
    }
#pragma unroll
    for (int i = 0; i < BN * CH / 256; ++i) {
      int p = i * 256 + t;
      int row = p / CH, c = (p & CM) ^ SWZ(row);
      __builtin_amdgcn_global_load_lds(
          GPTR(Bbase + (size_t)row * K + kt + c * 8),
          LPTR(Bs + (i * 256 + wid * 64) * 8), 16, 0, 0);
    }
  };

  int nIt = K / BK;
  stage(0, 0);
  if (nIt > 1) stage(1, BK);
  int cur = 0, nxt = 2;
  for (int it = 0; it < nIt; ++it) {
    if (it + 1 < nIt) {
      asm volatile("s_waitcnt vmcnt(%0)" :: "n"(LPT) : "memory");
    } else {
      asm volatile("s_waitcnt vmcnt(0)" ::: "memory");
    }
    __builtin_amdgcn_s_barrier();
    __builtin_amdgcn_sched_barrier(0);
    if (it + 2 < nIt) stage(nxt, (it + 2) * BK);
    const f16* As = sm + cur * TSZ;
    const f16* Bs = As + ASZ;
    f16x8 af[FM][KH], bf[FN][KH];
#pragma unroll
    for (int m = 0; m < FM; ++m) {
      int r = wr * (BM / 2) + m * 16 + rA;
#pragma unroll
      for (int h = 0; h < KH; ++h)
        af[m][h] = *(const f16x8*)&As[r * BK + (((h * 4 + kg) ^ SWZ(r)) * 8)];
    }
#pragma unroll
    for (int n = 0; n < FN; ++n) {
      int r = wc * (BN / 2) + n * 16 + rA;
#pragma unroll
      for (int h = 0; h < KH; ++h)
        bf[n][h] = *(const f16x8*)&Bs[r * BK + (((h * 4 + kg) ^ SWZ(r)) * 8)];
    }
#pragma unroll
    for (int h = 0; h < KH; ++h)
#pragma unroll
      for (int m = 0; m < FM; ++m)
#pragma unroll
        for (int n = 0; n < FN; ++n)
          acc[m][n] = MFMA16(af[m][h], bf[n][h], acc[m][n]);
    cur = (cur == 2) ? 0 : cur + 1;
    nxt = (nxt == 2) ? 0 : nxt + 1;
  }

  // ---- epilogue ---------------------------------------------------------
  if (ep == EPI_H || ep == EPI_RELU) {
    __builtin_amdgcn_s_barrier();
#pragma unroll
    for (int n = 0; n < FN; ++n) {
      int cl = wc * (BN / 2) + n * 16 + rA;
      float bvv = biasz[n0 + cl];
#pragma unroll
      for (int m = 0; m < FM; ++m) {
        int rl = wr * (BM / 2) + m * 16 + kg * 4;
#pragma unroll
        for (int r = 0; r < 4; ++r) {
          float v = acc[m][n][r] + bvv;
          if (ep == EPI_RELU) v = fmaxf(v, 0.0f);
          sm[(rl + r) * BN + cl] = (f16)v;
        }
      }
    }
    __syncthreads();
    f16* outp = outH + (size_t)z * zOut;
#pragma unroll
    for (int i = 0; i < BM * BN / 2048; ++i) {
      int p = i * 256 + t;
      int row = p / (BN / 8), c8 = p % (BN / 8);
      *(f16x8*)&outp[(size_t)(m0 + row) * N + n0 + c8 * 8] =
          *(const f16x8*)&sm[row * BN + c8 * 8];
    }
  } else {
#pragma unroll
    for (int n = 0; n < FN; ++n) {
      int gn = n0 + wc * (BN / 2) + n * 16 + rA;
      float bvv = biasz[gn];
#pragma unroll
      for (int m = 0; m < FM; ++m) {
        int gmb = m0 + wr * (BM / 2) + m * 16 + kg * 4;
        if (ep == EPI_VT) {
          f16x4 ov = { (f16)(acc[m][n][0] + bvv), (f16)(acc[m][n][1] + bvv),
                       (f16)(acc[m][n][2] + bvv), (f16)(acc[m][n][3] + bvv) };
          *(f16x4*)&outH[(size_t)z * zOut + (size_t)gn * NM + gmb] = ov;
        } else {
#pragma unroll
          for (int r = 0; r < 4; ++r) {
            int gm = gmb + r;
            outF[(size_t)gm * N + gn] =
                acc[m][n][r] + bvv + res[(size_t)gm * N + gn];
          }
        }
      }
    }
  }
}

// ---------------------------------------------------------------------------
// Role-gated flash attention.  grid 512, 256 threads = 4 waves, 32 q/wave.
// 2-buffer KV (48 KB LDS total -> 3 blocks/CU), double-barrier counted-vmcnt
// schedule.  Softmax reduction-free: Q pre-scaled by kC1,
// P = v_exp_f32(min(sc, 14.5)); denominator = P @ ones via MFMA.
// ---------------------------------------------------------------------------
__global__ __launch_bounds__(256) void attn_kernel(
    const f16* __restrict__ Qm, const f16* __restrict__ Km,
    const f16* __restrict__ Vt, const f16* __restrict__ Rm,
    f16* __restrict__ outA)
{
  int t = threadIdx.x, wid = t >> 6, lane = t & 63;
  int rA = lane & 15, kg = lane >> 4;
  int id = blockIdx.x;
  int j = id >> 3;
  int bh = (id & 7) * 8 + (j & 7), qb = j >> 3;   // XCD-contiguous per head
  int b = bh >> 4, h = bh & 15;
  int q0 = qb * 128 + wid * 32;

  __shared__ f16 KVs[2][2 * 64 * 64];   // 32 KB
  __shared__ f16 P[4][32 * 64];         // 16 KB
  f16* Pw = P[wid];

  f16x8 aq[2][2];
#pragma unroll
  for (int mf = 0; mf < 2; ++mf) {
    size_t qoff = (size_t)(b * NS + q0 + mf * 16 + rA) * HD + h * NDH + kg * 8;
    aq[mf][0] = *(const f16x8*)&Qm[qoff];
    aq[mf][1] = *(const f16x8*)&Qm[qoff + 32];
  }

  f32x4 o[2][4] = {};
  f32x4 osum[2] = {};
  f16x8 vones;
#pragma unroll
  for (int jj = 0; jj < 8; ++jj) vones[jj] = (f16)1.0f;

  auto stage = [&](int buf, int kv) {
    f16* Ks = KVs[buf];
    f16* Vs = Ks + 64 * 64;
#pragma unroll
    for (int i = 0; i < 2; ++i) {
      int p = i * 256 + t;
      int row = p >> 3, c16 = (p & 7) ^ (row & 7);
      __builtin_amdgcn_global_load_lds(
          GPTR(Km + (size_t)(b * NS + kv + row) * HD + h * NDH + c16 * 8),
          LPTR(Ks + (i * 256 + wid * 64) * 8), 16, 0, 0);
    }
#pragma unroll
    for (int i = 0; i < 2; ++i) {
      int p = i * 256 + t;
      int row = p >> 3, c16 = (p & 7) ^ (row & 7);
      __builtin_amdgcn_global_load_lds(
          GPTR(Vt + (size_t)(h * NDH + row) * NM + b * NS + kv + c16 * 8),
          LPTR(Vs + (i * 256 + wid * 64) * 8), 16, 0, 0);
    }
  };

  stage(0, 0);
  stage(1, 64);
  for (int tt = 0; tt < NS / 64; ++tt) {
    int cur = tt & 1;
    if (tt + 1 < NS / 64) {
      asm volatile("s_waitcnt vmcnt(4)" ::: "memory");
    } else {
      asm volatile("s_waitcnt vmcnt(0)" ::: "memory");
    }
    __builtin_amdgcn_s_barrier();
    __builtin_amdgcn_sched_barrier(0);
    const f16* Kc = KVs[cur];
    const f16* Vc = Kc + 64 * 64;

    // ---- scores: sc = (C1*Q) K^T  (C1 pre-folded into Q) ----------------
    f32x4 sc[2][4];
#pragma unroll
    for (int ct = 0; ct < 4; ++ct) {
      int krow = ct * 16 + rA;
      f16x8 kb0 = *(const f16x8*)&Kc[krow * 64 + ((kg ^ (rA & 7)) * 8)];
      f16x8 kb1 = *(const f16x8*)&Kc[krow * 64 + (((4 + kg) ^ (rA & 7)) * 8)];
#pragma unroll
      for (int mf = 0; mf < 2; ++mf) {
        f32x4 a = {};
        a = MFMA16(aq[mf][0], kb0, a);
        a = MFMA16(aq[mf][1], kb1, a);
        sc[mf][ct] = a;
      }
    }

    // ---- P = exp2(sc) via raw v_exp_f32, f16-overflow clamp -------------
#pragma unroll
    for (int mf = 0; mf < 2; ++mf)
#pragma unroll
      for (int ct = 0; ct < 4; ++ct)
#pragma unroll
        for (int r = 0; r < 4; ++r) {
          float arg = fminf(sc[mf][ct][r], 14.5f);
          float p;
          asm("v_exp_f32 %0, %1" : "=v"(p) : "v"(arg));
          Pw[(mf * 16 + kg * 4 + r) * 64 + ((ct ^ kg) * 16 + rA)] = (f16)p;
        }

    // ---- PV: o += P(32x64) @ V(64x64); osum += P @ ones -----------------
#pragma unroll
    for (int kc = 0; kc < 2; ++kc) {
      f16x8 vb[4];
#pragma unroll
      for (int dt = 0; dt < 4; ++dt)
        vb[dt] = *(const f16x8*)&Vc[(dt * 16 + rA) * 64 + (((kc * 4 + kg) ^ (rA & 7)) * 8)];
#pragma unroll
      for (int mf = 0; mf < 2; ++mf) {
        f16x8 pa = *(const f16x8*)&Pw[(mf * 16 + rA) * 64 + ((kc * 32 + kg * 8) ^ ((rA >> 2) << 4))];
#pragma unroll
        for (int dt = 0; dt < 4; ++dt)
          o[mf][dt] = MFMA16(pa, vb[dt], o[mf][dt]);
        osum[mf] = MFMA16(pa, vones, osum[mf]);
      }
    }
    if (tt + 2 < NS / 64) {
      __builtin_amdgcn_sched_barrier(0);
      __builtin_amdgcn_s_barrier();   // all waves done reading buf cur
      stage(cur, (tt + 2) * 64);      // overwrite cur; lands in ~1 full iter
    }
  }

  float lrinv[2][4];
#pragma unroll
  for (int mf = 0; mf < 2; ++mf)
#pragma unroll
    for (int r = 0; r < 4; ++r) lrinv[mf][r] = 1.0f / osum[mf][r];
#pragma unroll
  for (int mf = 0; mf < 2; ++mf)
#pragma unroll
    for (int dt = 0; dt < 4; ++dt)
#pragma unroll
      for (int r = 0; r < 4; ++r) {
        size_t idx = (size_t)(b * NS + q0 + mf * 16 + kg * 4 + r) * HD + h * NDH + dt * 16 + rA;
        float v = o[mf][dt][r] * lrinv[mf][r] * (float)Rm[idx];
        outA[idx] = (f16)v;
      }
}

// ---------------------------------------------------------------------------
// Host launcher
// ---------------------------------------------------------------------------
extern "C" void kernel_launch(void* const* d_in, const int* in_sizes, int n_in,
                              void* d_out, int out_size, void* d_ws, size_t ws_size,
                              hipStream_t stream)
{
  const float* src  = (const float*)d_in[0];
  const float* ln1g = (const float*)d_in[2];
  const float* ln1b = (const float*)d_in[3];
  const float* Wq   = (const float*)d_in[4];
  const float* bq   = (const float*)d_in[5];
  const float* Wk   = (const float*)d_in[6];
  const float* bk   = (const float*)d_in[7];
  const float* Wv   = (const float*)d_in[8];
  const float* bv   = (const float*)d_in[9];
  const float* Wr   = (const float*)d_in[10];
  const float* br   = (const float*)d_in[11];
  const float* Wo   = (const float*)d_in[12];
  const float* bo   = (const float*)d_in[13];
  const float* ln2g = (const float*)d_in[14];
  const float* ln2b = (const float*)d_in[15];
  const float* W1   = (const float*)d_in[16];
  const float* b1   = (const float*)d_in[17];
  const float* W2   = (const float*)d_in[18];
  const float* b2   = (const float*)d_in[19];
  const float* ln3g = (const float*)d_in[20];
  const float* ln3b = (const float*)d_in[21];

  // ---- workspace layout -------------------------------------------------
  char* ws = (char*)d_ws;
  float* biasbuf = (float*)ws;
  size_t off = 40960 * sizeof(float);
  const size_t WT_L = 13631488;  // f16 elements per layer: 5*1M + 4M + 4M
  size_t act_bytes = (size_t)NM * 1024 * 20;
  bool upfront = ws_size >= off + 4 * WT_L * 2 + act_bytes;
  f16* wt = (f16*)(ws + off);
  off += (upfront ? 4 : 1) * WT_L * 2;
  float* xbuf = (float*)(ws + off); off += (size_t)NM * ND * 4;
  float* mha  = (float*)(ws + off); off += (size_t)NM * ND * 4;
  f16* zbuf   = (f16*)(ws + off);   off += (size_t)NM * ND * 2;
  f16* qkvr   = (f16*)(ws + off);   off += (size_t)NM * ND * 2 * 4;  // also h1
  f16* aout   = (f16*)(ws + off);

  pack_bias<<<160, 256, 0, stream>>>(bq, bk, bv, br, bo, b1, b2, biasbuf);

  if (upfront) {
    transpose_cvt<<<dim3(16, 16, 4), 256, 0, stream>>>(Wq, wt + 0,       1024, 1024, 1048576, (int)WT_L);
    transpose_cvt<<<dim3(16, 16, 4), 256, 0, stream>>>(Wk, wt + 1048576, 1024, 1024, 1048576, (int)WT_L);
    transpose_cvt<<<dim3(16, 16, 4), 256, 0, stream>>>(Wv, wt + 2097152, 1024, 1024, 1048576, (int)WT_L);
    transpose_cvt<<<dim3(16, 16, 4), 256, 0, stream>>>(Wr, wt + 3145728, 1024, 1024, 1048576, (int)WT_L);
    transpose_cvt<<<dim3(16, 16, 4), 256, 0, stream>>>(Wo, wt + 4194304, 1024, 1024, 1048576, (int)WT_L);
    transpose_cvt<<<dim3(64, 16, 4), 256, 0, stream>>>(W1, wt + 5242880, 1024, 4096, 4194304, (int)WT_L);
    transpose_cvt<<<dim3(16, 64, 4), 256, 0, stream>>>(W2, wt + 9437184, 4096, 1024, 4194304, (int)WT_L);
  }

  for (int l = 0; l < 4; ++l) {
    f16* wtL = upfront ? wt + (size_t)l * WT_L : wt;
    const float* bL = biasbuf + l * 10240;
    if (!upfront) {
      transpose_cvt<<<dim3(16, 16, 1), 256, 0, stream>>>(Wq + (size_t)l * 1048576, wt + 0,       1024, 1024, 0, 0);
      transpose_cvt<<<dim3(16, 16, 1), 256, 0, stream>>>(Wk + (size_t)l * 1048576, wt + 1048576, 1024, 1024, 0, 0);
      transpose_cvt<<<dim3(16, 16, 1), 256, 0, stream>>>(Wv + (size_t)l * 1048576, wt + 2097152, 1024, 1024, 0, 0);
      transpose_cvt<<<dim3(16, 16, 1), 256, 0, stream>>>(Wr + (size_t)l * 1048576, wt + 3145728, 1024, 1024, 0, 0);
      transpose_cvt<<<dim3(16, 16, 1), 256, 0, stream>>>(Wo + (size_t)l * 1048576, wt + 4194304, 1024, 1024, 0, 0);
      transpose_cvt<<<dim3(64, 16, 1), 256, 0, stream>>>(W1 + (size_t)l * 4194304, wt + 5242880, 1024, 4096, 0, 0);
      transpose_cvt<<<dim3(16, 64, 1), 256, 0, stream>>>(W2 + (size_t)l * 4194304, wt + 9437184, 4096, 1024, 0, 0);
    }
    const float* xin = l ? xbuf : src;

    // z = LN1(x)
    ln_kernel<true><<<NM, 256, 0, stream>>>(xin, ln1g + l * 1024, ln1b + l * 1024, zbuf);
    // Q,K,Vt,R = z @ [Wq|Wk|Wv|Wr] + b  (unified N=4096; Q scaled by kC1;
    // V written transposed)
    gemm256<EPI_QKVR><<<dim3(16, 16), 512, 0, stream>>>(zbuf, wtL, bL, qkvr, 1024);
    // gated attention -> aout (f16)
    attn_kernel<<<dim3(512), 256, 0, stream>>>(
        qkvr, qkvr + 4194304, qkvr + 8388608, qkvr + 12582912, aout);
    // mha = x + aout @ Wo + bo
    gemm_bt<128, 64, 64><<<dim3(32, 16, 1), 256, 0, stream>>>(
        aout, wtL + 4194304, bL + 4096, xin, nullptr, mha, 1024, 1024, EPI_RESF32, 0, 0, 0);
    // z2 = LN2(mha)
    ln_kernel<true><<<NM, 256, 0, stream>>>(mha, ln2g + l * 1024, ln2b + l * 1024, zbuf);
    // h1 = relu(z2 @ W1 + b1)   (reuses QKVR buffer, N=4096)
    gemm256<EPI_RELU><<<dim3(16, 16), 512, 0, stream>>>(zbuf, wtL + 5242880, bL + 5120, qkvr, 1024);
    // mha = mha + h1 @ W2 + b2   (in-place residual)
    gemm_bt<128, 64, 64><<<dim3(32, 16, 1), 256, 0, stream>>>(
        qkvr, wtL + 9437184, bL + 9216, mha, nullptr, mha, 1024, 4096, EPI_RESF32, 0, 0, 0);
    // x_next = LN3(mha)   (last layer -> d_out, f32)
    float* lnout = (l == 3) ? (float*)d_out : xbuf;
    ln_kernel<false><<<NM, 256, 0, stream>>>(mha, ln3g + l * 1024, ln3b + l * 1024, lnout);
  }
}

// Round 18
// 821.960 us; speedup vs baseline: 1.0786x; 1.0426x over previous
//
#include <hip/hip_runtime.h>

// ---------------------------------------------------------------------------
// Encoder: 4 layers of {LN1 -> QKVR proj -> role-gated attention -> Wo+res ->
// LN2 -> FFN(relu) + res -> LN3}.  B=4 S=1024 D=1024 H=16 DH=64 DF=4096.
// f32 I/O; internal GEMMs in fp16 MFMA (16x16x32) with f32 accumulate.
// N=4096 GEMMs (QKVR-unified, W1): 256x256xBK64 8-wave quadrant-phase kernel.
// N=1024 K-large GEMMs (Wo, W2): 128x64xBK64 3-buffer pipeline.
// R17: residual stream mha held in f16 (traffic halved on 5 tensors/layer);
// LN3+LN1 fused into one kernel (saves a 16 MB re-read + dispatch / layer).
// Attention: reduction-free softmax (clamped raw v_exp_f32 + ones-column
// MFMA denominator); C1 pre-folded into Q; 2-buffer KV, counted vmcnt.
// ---------------------------------------------------------------------------

typedef _Float16 f16;
typedef _Float16 f16x8 __attribute__((ext_vector_type(8)));
typedef _Float16 f16x4 __attribute__((ext_vector_type(4)));
typedef float    f32x4 __attribute__((ext_vector_type(4)));

#define GPTR(x) (const __attribute__((address_space(1))) void*)(x)
#define LPTR(x) (__attribute__((address_space(3))) void*)(x)
#define MFMA16(a,b,c) __builtin_amdgcn_mfma_f32_16x16x32_f16(a, b, c, 0, 0, 0)

static constexpr int NB   = 4;      // batch
static constexpr int NS   = 1024;   // seq
static constexpr int ND   = 1024;   // d_model
static constexpr int NH   = 16;     // heads
static constexpr int NDH  = 64;     // head dim
static constexpr int NDF  = 4096;   // ffn
static constexpr int NM   = NB * NS;        // 4096 rows
static constexpr int HD   = NH * NDH;       // 1024
static constexpr float kC1 = 0.180336879f;  // 0.125 * log2(e)

// epilogue modes
#define EPI_H      0   // outH[m*N+n] = acc + bias
#define EPI_VT     1   // outH[n*NM+m] = acc + bias   (V transposed)
#define EPI_RELU   2   // outH[m*N+n] = relu(acc + bias)
#define EPI_RESO16 3   // outH f16 = acc + bias + res(f32)
#define EPI_QKVR   4   // z==2 -> VT; z==0 scaled by kC1; else EPI_H
#define EPI_RESH16 5   // outH f16 = acc + bias + res(f16)  (in-place capable)

// ---------------------------------------------------------------------------
// Weight transpose + f32->f16 convert: src (R,C) row-major f32 -> dst (C,R) f16
// ---------------------------------------------------------------------------
__global__ __launch_bounds__(256) void transpose_cvt(
    const float* __restrict__ src, f16* __restrict__ dst,
    int R, int C, int srcZ, int dstZ)
{
  src += (size_t)blockIdx.z * srcZ;
  dst += (size_t)blockIdx.z * dstZ;
  __shared__ float tile[64][65];
  int t  = threadIdx.x;
  int c0 = blockIdx.x * 64, r0 = blockIdx.y * 64;
  int tr = t >> 4, tc4 = (t & 15) * 4;
#pragma unroll
  for (int i = 0; i < 4; ++i) {
    float4 v = *(const float4*)&src[(size_t)(r0 + tr + i * 16) * C + c0 + tc4];
    tile[tr + i * 16][tc4 + 0] = v.x;
    tile[tr + i * 16][tc4 + 1] = v.y;
    tile[tr + i * 16][tc4 + 2] = v.z;
    tile[tr + i * 16][tc4 + 3] = v.w;
  }
  __syncthreads();
  int n = t >> 2, ks = (t & 3) * 16;
  f16x8 o0, o1;
#pragma unroll
  for (int j = 0; j < 8; ++j) {
    o0[j] = (f16)tile[ks + j][n];
    o1[j] = (f16)tile[ks + 8 + j][n];
  }
  f16* dp = &dst[(size_t)(c0 + n) * R + r0 + ks];
  *(f16x8*)dp       = o0;
  *(f16x8*)(dp + 8) = o1;
}

// ---------------------------------------------------------------------------
// Pack the 7 bias arrays into one contiguous buffer.
// ---------------------------------------------------------------------------
__global__ __launch_bounds__(256) void pack_bias(
    const float* __restrict__ bq, const float* __restrict__ bk,
    const float* __restrict__ bv, const float* __restrict__ br,
    const float* __restrict__ bo, const float* __restrict__ b1,
    const float* __restrict__ b2, float* __restrict__ dst)
{
  int i = blockIdx.x * 256 + threadIdx.x;
  if (i >= 4 * 10240) return;
  int l = i / 10240, o = i % 10240;
  float v;
  if      (o < 1024) v = bq[l * 1024 + o];
  else if (o < 2048) v = bk[l * 1024 + o - 1024];
  else if (o < 3072) v = bv[l * 1024 + o - 2048];
  else if (o < 4096) v = br[l * 1024 + o - 3072];
  else if (o < 5120) v = bo[l * 1024 + o - 4096];
  else if (o < 9216) v = b1[l * 4096 + o - 5120];
  else               v = b2[l * 1024 + o - 9216];
  dst[i] = v;
}

// ---------------------------------------------------------------------------
// LayerNorm over D=1024: one row per block, 256 threads x 4 elements.
// F16IN: input f16 (mha stream); else f32.  F16OUT: f16 (GEMM operand).
// ---------------------------------------------------------------------------
template<bool F16IN, bool F16OUT>
__global__ __launch_bounds__(256) void ln_kernel(
    const void* __restrict__ in, const float* __restrict__ g,
    const float* __restrict__ b, void* __restrict__ out)
{
  int row = blockIdx.x, t = threadIdx.x;
  float x0, x1, x2, x3;
  if (F16IN) {
    f16x4 v = *(const f16x4*)((const f16*)in + (size_t)row * ND + t * 4);
    x0 = (float)v[0]; x1 = (float)v[1]; x2 = (float)v[2]; x3 = (float)v[3];
  } else {
    float4 v = *(const float4*)((const float*)in + (size_t)row * ND + t * 4);
    x0 = v.x; x1 = v.y; x2 = v.z; x3 = v.w;
  }
  float s  = x0 + x1 + x2 + x3;
  float sq = x0 * x0 + x1 * x1 + x2 * x2 + x3 * x3;
#pragma unroll
  for (int off = 32; off; off >>= 1) {
    s  += __shfl_xor(s, off, 64);
    sq += __shfl_xor(sq, off, 64);
  }
  __shared__ float rb[8];
  int wid = t >> 6;
  if ((t & 63) == 0) { rb[wid] = s; rb[4 + wid] = sq; }
  __syncthreads();
  s  = rb[0] + rb[1] + rb[2] + rb[3];
  sq = rb[4] + rb[5] + rb[6] + rb[7];
  float mean = s * (1.0f / ND);
  float var  = sq * (1.0f / ND) - mean * mean;
  float rstd = rsqrtf(var + 1e-5f);
  float4 g4 = *(const float4*)&g[t * 4];
  float4 b4 = *(const float4*)&b[t * 4];
  float o0 = (x0 - mean) * rstd * g4.x + b4.x;
  float o1 = (x1 - mean) * rstd * g4.y + b4.y;
  float o2 = (x2 - mean) * rstd * g4.z + b4.z;
  float o3 = (x3 - mean) * rstd * g4.w + b4.w;
  if (F16OUT) {
    f16x4 ov = { (f16)o0, (f16)o1, (f16)o2, (f16)o3 };
    *(f16x4*)((f16*)out + (size_t)row * ND + t * 4) = ov;
  } else {
    float4 ov = { o0, o1, o2, o3 };
    *(float4*)((float*)out + (size_t)row * ND + t * 4) = ov;
  }
}

// ---------------------------------------------------------------------------
// Fused LN3 -> LN1(next layer).  in = mha2 (f16).  y = LN3(in) written f32
// (residual stream for next layer, or d_out on LAST); z = LN1(y) written f16
// (QKVR operand) unless LAST.
// ---------------------------------------------------------------------------
template<bool LAST>
__global__ __launch_bounds__(256) void ln3ln1_kernel(
    const f16* __restrict__ in, const float* __restrict__ g3,
    const float* __restrict__ b3, const float* __restrict__ g1,
    const float* __restrict__ b1, float* __restrict__ yout,
    f16* __restrict__ zout)
{
  int row = blockIdx.x, t = threadIdx.x;
  f16x4 v = *(const f16x4*)&in[(size_t)row * ND + t * 4];
  float x0 = (float)v[0], x1 = (float)v[1], x2 = (float)v[2], x3 = (float)v[3];
  float s  = x0 + x1 + x2 + x3;
  float sq = x0 * x0 + x1 * x1 + x2 * x2 + x3 * x3;
#pragma unroll
  for (int off = 32; off; off >>= 1) {
    s  += __shfl_xor(s, off, 64);
    sq += __shfl_xor(sq, off, 64);
  }
  __shared__ float rb[16];
  int wid = t >> 6;
  if ((t & 63) == 0) { rb[wid] = s; rb[4 + wid] = sq; }
  __syncthreads();
  s  = rb[0] + rb[1] + rb[2] + rb[3];
  sq = rb[4] + rb[5] + rb[6] + rb[7];
  float mean = s * (1.0f / ND);
  float var  = sq * (1.0f / ND) - mean * mean;
  float rstd = rsqrtf(var + 1e-5f);
  float4 g4 = *(const float4*)&g3[t * 4];
  float4 b4 = *(const float4*)&b3[t * 4];
  float y0 = (x0 - mean) * rstd * g4.x + b4.x;
  float y1 = (x1 - mean) * rstd * g4.y + b4.y;
  float y2 = (x2 - mean) * rstd * g4.z + b4.z;
  float y3 = (x3 - mean) * rstd * g4.w + b4.w;
  float4 yv = { y0, y1, y2, y3 };
  *(float4*)&yout[(size_t)row * ND + t * 4] = yv;
  if (!LAST) {
    float s2  = y0 + y1 + y2 + y3;
    float q2  = y0 * y0 + y1 * y1 + y2 * y2 + y3 * y3;
#pragma unroll
    for (int off = 32; off; off >>= 1) {
      s2 += __shfl_xor(s2, off, 64);
      q2 += __shfl_xor(q2, off, 64);
    }
    if ((t & 63) == 0) { rb[8 + wid] = s2; rb[12 + wid] = q2; }
    __syncthreads();
    s2 = rb[8] + rb[9] + rb[10] + rb[11];
    q2 = rb[12] + rb[13] + rb[14] + rb[15];
    float mean2 = s2 * (1.0f / ND);
    float var2  = q2 * (1.0f / ND) - mean2 * mean2;
    float rstd2 = rsqrtf(var2 + 1e-5f);
    float4 g14 = *(const float4*)&g1[t * 4];
    float4 b14 = *(const float4*)&b1[t * 4];
    f16x4 zv = { (f16)((y0 - mean2) * rstd2 * g14.x + b14.x),
                 (f16)((y1 - mean2) * rstd2 * g14.y + b14.y),
                 (f16)((y2 - mean2) * rstd2 * g14.z + b14.z),
                 (f16)((y3 - mean2) * rstd2 * g14.w + b14.w) };
    *(f16x4*)&zout[(size_t)row * ND + t * 4] = zv;
  }
}

// ---------------------------------------------------------------------------
// gemm256: C(4096 x 4096) = A(4096 x K) * Bt(4096 x K)^T + bias, f16 out.
// 256x256xBK64, 512 threads = 8 waves; quadrant-phase K-loop (unchanged,
// best-measured).  EPI_QKVR: z==2 writes V^T; z==0 (Q) scaled by kC1.
// ---------------------------------------------------------------------------
template<int EPIMODE>
__global__ __launch_bounds__(512, 2) void gemm256(
    const f16* __restrict__ A, const f16* __restrict__ Bt,
    const float* __restrict__ bias, f16* __restrict__ outH, int K)
{
  constexpr int BM = 256, BN = 256, BK = 64;
  constexpr int ASZ = BM * BK;
  constexpr int TSZ = 2 * ASZ;
  __shared__ f16 sm[2 * TSZ];

  int lin = blockIdx.x + (blockIdx.y << 4);
  int l2  = (lin & 7) * 32 + (lin >> 3);
  int by  = l2 & 15, bx = l2 >> 4;

  int t = threadIdx.x;
  int wid = t >> 6, lane = t & 63;
  int wr = wid >> 2, wc = wid & 3;
  int rA = lane & 15, kg = lane >> 4;
  int m0 = bx * BM, n0 = by * BN;

  f32x4 acc[8][4] = {};
  const f16* Abase = A  + (size_t)m0 * K;
  const f16* Bbase = Bt + (size_t)n0 * K;

  auto stage = [&](int buf, int kt) {
    f16* As = sm + buf * TSZ;
    f16* Bs = As + ASZ;
#pragma unroll
    for (int i = 0; i < 4; ++i) {
      int p = i * 512 + t;
      int row = p >> 3, c = (p & 7) ^ (row & 7);
      __builtin_amdgcn_global_load_lds(
          GPTR(Abase + (size_t)row * K + kt + c * 8),
          LPTR(As + (i * 512 + wid * 64) * 8), 16, 0, 0);
    }
#pragma unroll
    for (int i = 0; i < 4; ++i) {
      int p = i * 512 + t;
      int row = p >> 3, c = (p & 7) ^ (row & 7);
      __builtin_amdgcn_global_load_lds(
          GPTR(Bbase + (size_t)row * K + kt + c * 8),
          LPTR(Bs + (i * 512 + wid * 64) * 8), 16, 0, 0);
    }
  };

  int nIt = K / BK;                    // 16
  stage(0, 0);
  stage(1, BK);
  for (int it = 0; it < nIt; ++it) {
    int cur = it & 1;
    if (it + 1 < nIt) {
      asm volatile("s_waitcnt vmcnt(8)" ::: "memory");
    } else {
      asm volatile("s_waitcnt vmcnt(0)" ::: "memory");
    }
    __builtin_amdgcn_s_barrier();
    __builtin_amdgcn_sched_barrier(0);
    const f16* As = sm + cur * TSZ;
    const f16* Bs = As + ASZ;
    f16x8 af[8][2], bf[4][2];

    // ---- phase 0: (m0-3, n0-1); reads af[0..3], bf[0..1] ----------------
#pragma unroll
    for (int m = 0; m < 4; ++m) {
      int r = wr * 128 + m * 16 + rA;
#pragma unroll
      for (int h = 0; h < 2; ++h)
        af[m][h] = *(const f16x8*)&As[r * BK + (((h * 4 + kg) ^ (r & 7)) * 8)];
    }
#pragma unroll
    for (int n = 0; n < 2; ++n) {
      int r = wc * 64 + n * 16 + rA;
#pragma unroll
      for (int h = 0; h < 2; ++h)
        bf[n][h] = *(const f16x8*)&Bs[r * BK + (((h * 4 + kg) ^ (r & 7)) * 8)];
    }
    asm volatile("s_waitcnt lgkmcnt(0)" ::: "memory");
    __builtin_amdgcn_sched_barrier(0);
    __builtin_amdgcn_s_setprio(1);
#pragma unroll
    for (int h = 0; h < 2; ++h)
#pragma unroll
      for (int m = 0; m < 4; ++m)
#pragma unroll
        for (int n = 0; n < 2; ++n)
          acc[m][n] = MFMA16(af[m][h], bf[n][h], acc[m][n]);
    __builtin_amdgcn_s_setprio(0);
    __builtin_amdgcn_sched_barrier(0);
    __builtin_amdgcn_s_barrier();

    // ---- phase 1: (m0-3, n2-3); reads bf[2..3] --------------------------
#pragma unroll
    for (int n = 2; n < 4; ++n) {
      int r = wc * 64 + n * 16 + rA;
#pragma unroll
      for (int h = 0; h < 2; ++h)
        bf[n][h] = *(const f16x8*)&Bs[r * BK + (((h * 4 + kg) ^ (r & 7)) * 8)];
    }
    asm volatile("s_waitcnt lgkmcnt(0)" ::: "memory");
    __builtin_amdgcn_sched_barrier(0);
    __builtin_amdgcn_s_setprio(1);
#pragma unroll
    for (int h = 0; h < 2; ++h)
#pragma unroll
      for (int m = 0; m < 4; ++m)
#pragma unroll
        for (int n = 2; n < 4; ++n)
          acc[m][n] = MFMA16(af[m][h], bf[n][h], acc[m][n]);
    __builtin_amdgcn_s_setprio(0);
    __builtin_amdgcn_sched_barrier(0);
    __builtin_amdgcn_s_barrier();

    // ---- phase 2: (m4-7, n0-1); reads af[4..7] --------------------------
#pragma unroll
    for (int m = 4; m < 8; ++m) {
      int r = wr * 128 + m * 16 + rA;
#pragma unroll
      for (int h = 0; h < 2; ++h)
        af[m][h] = *(const f16x8*)&As[r * BK + (((h * 4 + kg) ^ (r & 7)) * 8)];
    }
    asm volatile("s_waitcnt lgkmcnt(0)" ::: "memory");
    __builtin_amdgcn_sched_barrier(0);
    __builtin_amdgcn_s_setprio(1);
#pragma unroll
    for (int h = 0; h < 2; ++h)
#pragma unroll
      for (int m = 4; m < 8; ++m)
#pragma unroll
        for (int n = 0; n < 2; ++n)
          acc[m][n] = MFMA16(af[m][h], bf[n][h], acc[m][n]);
    __builtin_amdgcn_s_setprio(0);
    __builtin_amdgcn_sched_barrier(0);
    __builtin_amdgcn_s_barrier();

    // ---- phase 3: (m4-7, n2-3); no reads -> issue next-next stage -------
    if (it + 2 < nIt) stage(cur, (it + 2) * BK);
    __builtin_amdgcn_s_setprio(1);
#pragma unroll
    for (int h = 0; h < 2; ++h)
#pragma unroll
      for (int m = 4; m < 8; ++m)
#pragma unroll
        for (int n = 2; n < 4; ++n)
          acc[m][n] = MFMA16(af[m][h], bf[n][h], acc[m][n]);
    __builtin_amdgcn_s_setprio(0);
    __builtin_amdgcn_sched_barrier(0);
  }

  // ---- epilogue (fragment: C row = kg*4 + r, col = rA) -------------------
  __builtin_amdgcn_s_barrier();
  if (EPIMODE == EPI_QKVR && (n0 >> 10) == 2) {
    f16* vt = outH + (size_t)2 * 4194304;
#pragma unroll
    for (int n = 0; n < 4; ++n) {
      int gn = n0 + wc * 64 + n * 16 + rA;
      int gnl = gn & 1023;
      float bvv = bias[gn];
#pragma unroll
      for (int m = 0; m < 8; ++m) {
        int gmb = m0 + wr * 128 + m * 16 + kg * 4;
        f16x4 ov = { (f16)(acc[m][n][0] + bvv), (f16)(acc[m][n][1] + bvv),
                     (f16)(acc[m][n][2] + bvv), (f16)(acc[m][n][3] + bvv) };
        *(f16x4*)&vt[(size_t)gnl * NM + gmb] = ov;
      }
    }
  } else {
    bool scaleQ = (EPIMODE == EPI_QKVR) && ((n0 >> 10) == 0);
#pragma unroll
    for (int n = 0; n < 4; ++n) {
      int cl = wc * 64 + n * 16 + rA;
      float bvv = bias[n0 + cl];
#pragma unroll
      for (int m = 0; m < 8; ++m) {
        int rl = wr * 128 + m * 16 + kg * 4;
#pragma unroll
        for (int r = 0; r < 4; ++r) {
          float v = acc[m][n][r] + bvv;
          if (EPIMODE == EPI_RELU) v = fmaxf(v, 0.0f);
          if (scaleQ) v *= kC1;
          sm[(rl + r) * 256 + cl] = (f16)v;
        }
      }
    }
    __syncthreads();
    f16* outp;
    int ldo, col0;
    if (EPIMODE == EPI_QKVR) {
      int z = n0 >> 10;
      outp = outH + (size_t)z * 4194304; ldo = 1024; col0 = n0 & 1023;
    } else {
      outp = outH; ldo = 4096; col0 = n0;
    }
#pragma unroll
    for (int i = 0; i < 16; ++i) {
      int p = i * 512 + t;
      int row = p >> 5, c8 = p & 31;
      *(f16x8*)&outp[(size_t)(m0 + row) * ldo + col0 + c8 * 8] =
          *(const f16x8*)&sm[row * 256 + c8 * 8];
    }
  }
}

// ---------------------------------------------------------------------------
// GEMM: C(M x N) = A(M x K) * Bt(N x K)^T + bias (+ residual / relu / VT).
// 3-buffer counted-vmcnt pipeline.  Used for Wo (EPI_RESO16: res f32 ->
// f16 out) and W2 (EPI_RESH16: res f16, in-place f16 out).  All f16
// row-major outputs go through the LDS-staged coalesced epilogue.
// ---------------------------------------------------------------------------
template<int BM, int BN, int BK>
__global__ __launch_bounds__(256) void gemm_bt(
    const f16* __restrict__ A, const f16* __restrict__ Bt,
    const float* __restrict__ bias, const float* __restrict__ res,
    f16* __restrict__ outH, float* __restrict__ outF,
    int N, int K, int epi, int zBt, int zBias, int zOut)
{
  constexpr int CH = BK / 8;
  constexpr int CM = CH - 1;
  constexpr int KH = BK / 32;
  constexpr int FM = BM / 32, FN = BN / 32;
  constexpr int ASZ = BM * BK, BSZ = BN * BK;
  constexpr int TSZ = ASZ + BSZ;
  constexpr int LPT = (BM + BN) * CH / 256;
  constexpr int SMEM = (3 * TSZ > BM * BN) ? 3 * TSZ : BM * BN;
  __shared__ f16 sm[SMEM];

  auto SWZ = [](int row) { return ((CH == 4) ? (row >> 1) : row) & CM; };

  int nx = gridDim.x, ny = gridDim.y;
  int lin = blockIdx.x + nx * (blockIdx.y + ny * blockIdx.z);
  int tot = nx * ny * gridDim.z;
  int l2  = (lin & 7) * (tot >> 3) + (lin >> 3);
  int by  = l2 % ny; int rem = l2 / ny; int bx = rem % nx; int z = rem / nx;

  Bt += (size_t)z * zBt;
  const float* biasz = bias + (size_t)z * zBias;
  int ep = (epi == EPI_QKVR) ? ((z == 2) ? EPI_VT : EPI_H) : epi;

  int t = threadIdx.x;
  int wid = t >> 6, lane = t & 63;
  int wr = wid >> 1, wc = wid & 1;
  int rA = lane & 15, kg = lane >> 4;
  int m0 = bx * BM, n0 = by * BN;

  f32x4 acc[FM][FN] = {};
  const f16* Abase = A  + (size_t)m0 * K;
  const f16* Bbase = Bt + (size_t)n0 * K;

  auto stage = [&](int buf, int kt) {
    f16* As = sm + buf * TSZ;
    f16* Bs = As + ASZ;
#pragma unroll
    for (int i = 0; i < BM * CH / 256; ++i) {
      int p = i * 256 + t;
      int row = p / CH, c = (p & CM) ^ SWZ(row);
      __builtin_amdgcn_global_load_lds(
          GPTR(Abase + (size_t)row * K + kt + c * 8),
          LPTR(As + (i * 256 + wid * 64) * 8), 16, 0, 0);
    }
#pragma unroll
    for (int i = 0; i < BN * CH / 256; ++i) {
      int p = i * 256 + t;
      int row = p / CH, c = (p & CM) ^ SWZ(row);
      __builtin_amdgcn_global_load_lds(
          GPTR(Bbase + (size_t)row * K + kt + c * 8),
          LPTR(Bs + (i * 256 + wid * 64) * 8), 16, 0, 0);
    }
  };

  int nIt = K / BK;
  stage(0, 0);
  if (nIt > 1) stage(1, BK);
  int cur = 0, nxt = 2;
  for (int it = 0; it < nIt; ++it) {
    if (it + 1 < nIt) {
      asm volatile("s_waitcnt vmcnt(%0)" :: "n"(LPT) : "memory");
    } else {
      asm volatile("s_waitcnt vmcnt(0)" ::: "memory");
    }
    __builtin_amdgcn_s_barrier();
    __builtin_amdgcn_sched_barrier(0);
    if (it + 2 < nIt) stage(nxt, (it + 2) * BK);
    const f16* As = sm + cur * TSZ;
    const f16* Bs = As + ASZ;
    f16x8 af[FM][KH], bf[FN][KH];
#pragma unroll
    for (int m = 0; m < FM; ++m) {
      int r = wr * (BM / 2) + m * 16 + rA;
#pragma unroll
      for (int h = 0; h < KH; ++h)
        af[m][h] = *(const f16x8*)&As[r * BK + (((h * 4 + kg) ^ SWZ(r)) * 8)];
    }
#pragma unroll
    for (int n = 0; n < FN; ++n) {
      int r = wc * (BN / 2) + n * 16 + rA;
#pragma unroll
      for (int h = 0; h < KH; ++h)
        bf[n][h] = *(const f16x8*)&Bs[r * BK + (((h * 4 + kg) ^ SWZ(r)) * 8)];
    }
#pragma unroll
    for (int h = 0; h < KH; ++h)
#pragma unroll
      for (int m = 0; m < FM; ++m)
#pragma unroll
        for (int n = 0; n < FN; ++n)
          acc[m][n] = MFMA16(af[m][h], bf[n][h], acc[m][n]);
    cur = (cur == 2) ? 0 : cur + 1;
    nxt = (nxt == 2) ? 0 : nxt + 1;
  }

  // ---- epilogue (fragment: C row = kg*4 + r, col = rA) -------------------
  if (ep == EPI_VT) {
#pragma unroll
    for (int n = 0; n < FN; ++n) {
      int gn = n0 + wc * (BN / 2) + n * 16 + rA;
      float bvv = biasz[gn];
#pragma unroll
      for (int m = 0; m < FM; ++m) {
        int gmb = m0 + wr * (BM / 2) + m * 16 + kg * 4;
        f16x4 ov = { (f16)(acc[m][n][0] + bvv), (f16)(acc[m][n][1] + bvv),
                     (f16)(acc[m][n][2] + bvv), (f16)(acc[m][n][3] + bvv) };
        *(f16x4*)&outH[(size_t)z * zOut + (size_t)gn * NM + gmb] = ov;
      }
    }
  } else {
    // LDS-staged coalesced f16 writeout (with optional residual add)
    __builtin_amdgcn_sched_barrier(0);
    __builtin_amdgcn_s_barrier();   // all waves done reading sm
#pragma unroll
    for (int n = 0; n < FN; ++n) {
      int cl = wc * (BN / 2) + n * 16 + rA;
      float bvv = biasz[n0 + cl];
#pragma unroll
      for (int m = 0; m < FM; ++m) {
        int rl = wr * (BM / 2) + m * 16 + kg * 4;
#pragma unroll
        for (int r = 0; r < 4; ++r) {
          float v = acc[m][n][r] + bvv;
          if (ep == EPI_RELU) v = fmaxf(v, 0.0f);
          sm[(rl + r) * BN + cl] = (f16)v;
        }
      }
    }
    __syncthreads();
    f16* outp = outH + (size_t)z * zOut;
#pragma unroll
    for (int i = 0; i < BM * BN / 2048; ++i) {
      int p = i * 256 + t;
      int row = p / (BN / 8), c8 = p % (BN / 8);
      size_t gidx = (size_t)(m0 + row) * N + n0 + c8 * 8;
      f16x8 sv = *(const f16x8*)&sm[row * BN + c8 * 8];
      if (ep == EPI_RESO16) {
        const float* rp = res + gidx;
        float4 ra = *(const float4*)rp;
        float4 rc = *(const float4*)(rp + 4);
        f16x8 ov;
        ov[0] = (f16)((float)sv[0] + ra.x);
        ov[1] = (f16)((float)sv[1] + ra.y);
        ov[2] = (f16)((float)sv[2] + ra.z);
        ov[3] = (f16)((float)sv[3] + ra.w);
        ov[4] = (f16)((float)sv[4] + rc.x);
        ov[5] = (f16)((float)sv[5] + rc.y);
        ov[6] = (f16)((float)sv[6] + rc.z);
        ov[7] = (f16)((float)sv[7] + rc.w);
        *(f16x8*)&outp[gidx] = ov;
      } else if (ep == EPI_RESH16) {
        const f16* rh = (const f16*)res;
        f16x8 rv = *(const f16x8*)&rh[gidx];
        f16x8 ov;
#pragma unroll
        for (int j = 0; j < 8; ++j)
          ov[j] = (f16)((float)sv[j] + (float)rv[j]);
        *(f16x8*)&outp[gidx] = ov;
      } else {
        *(f16x8*)&outp[gidx] = sv;
      }
    }
  }
}

// ---------------------------------------------------------------------------
// Role-gated flash attention.  grid 512, 256 threads = 4 waves, 32 q/wave.
// 2-buffer KV (48 KB LDS -> 3 blocks/CU), double-barrier counted-vmcnt.
// Softmax reduction-free: Q pre-scaled by kC1, P = v_exp_f32(min(sc,14.5));
// denominator = P @ ones via MFMA.
// ---------------------------------------------------------------------------
__global__ __launch_bounds__(256) void attn_kernel(
    const f16* __restrict__ Qm, const f16* __restrict__ Km,
    const f16* __restrict__ Vt, const f16* __restrict__ Rm,
    f16* __restrict__ outA)
{
  int t = threadIdx.x, wid = t >> 6, lane = t & 63;
  int rA = lane & 15, kg = lane >> 4;
  int id = blockIdx.x;
  int j = id >> 3;
  int bh = (id & 7) * 8 + (j & 7), qb = j >> 3;   // XCD-contiguous per head
  int b = bh >> 4, h = bh & 15;
  int q0 = qb * 128 + wid * 32;

  __shared__ f16 KVs[2][2 * 64 * 64];   // 32 KB
  __shared__ f16 P[4][32 * 64];         // 16 KB
  f16* Pw = P[wid];

  f16x8 aq[2][2];
#pragma unroll
  for (int mf = 0; mf < 2; ++mf) {
    size_t qoff = (size_t)(b * NS + q0 + mf * 16 + rA) * HD + h * NDH + kg * 8;
    aq[mf][0] = *(const f16x8*)&Qm[qoff];
    aq[mf][1] = *(const f16x8*)&Qm[qoff + 32];
  }

  f32x4 o[2][4] = {};
  f32x4 osum[2] = {};
  f16x8 vones;
#pragma unroll
  for (int jj = 0; jj < 8; ++jj) vones[jj] = (f16)1.0f;

  auto stage = [&](int buf, int kv) {
    f16* Ks = KVs[buf];
    f16* Vs = Ks + 64 * 64;
#pragma unroll
    for (int i = 0; i < 2; ++i) {
      int p = i * 256 + t;
      int row = p >> 3, c16 = (p & 7) ^ (row & 7);
      __builtin_amdgcn_global_load_lds(
          GPTR(Km + (size_t)(b * NS + kv + row) * HD + h * NDH + c16 * 8),
          LPTR(Ks + (i * 256 + wid * 64) * 8), 16, 0, 0);
    }
#pragma unroll
    for (int i = 0; i < 2; ++i) {
      int p = i * 256 + t;
      int row = p >> 3, c16 = (p & 7) ^ (row & 7);
      __builtin_amdgcn_global_load_lds(
          GPTR(Vt + (size_t)(h * NDH + row) * NM + b * NS + kv + c16 * 8),
          LPTR(Vs + (i * 256 + wid * 64) * 8), 16, 0, 0);
    }
  };

  stage(0, 0);
  stage(1, 64);
  for (int tt = 0; tt < NS / 64; ++tt) {
    int cur = tt & 1;
    if (tt + 1 < NS / 64) {
      asm volatile("s_waitcnt vmcnt(4)" ::: "memory");
    } else {
      asm volatile("s_waitcnt vmcnt(0)" ::: "memory");
    }
    __builtin_amdgcn_s_barrier();
    __builtin_amdgcn_sched_barrier(0);
    const f16* Kc = KVs[cur];
    const f16* Vc = Kc + 64 * 64;

    f32x4 sc[2][4];
#pragma unroll
    for (int ct = 0; ct < 4; ++ct) {
      int krow = ct * 16 + rA;
      f16x8 kb0 = *(const f16x8*)&Kc[krow * 64 + ((kg ^ (rA & 7)) * 8)];
      f16x8 kb1 = *(const f16x8*)&Kc[krow * 64 + (((4 + kg) ^ (rA & 7)) * 8)];
#pragma unroll
      for (int mf = 0; mf < 2; ++mf) {
        f32x4 a = {};
        a = MFMA16(aq[mf][0], kb0, a);
        a = MFMA16(aq[mf][1], kb1, a);
        sc[mf][ct] = a;
      }
    }

#pragma unroll
    for (int mf = 0; mf < 2; ++mf)
#pragma unroll
      for (int ct = 0; ct < 4; ++ct)
#pragma unroll
        for (int r = 0; r < 4; ++r) {
          float arg = fminf(sc[mf][ct][r], 14.5f);
          float p;
          asm("v_exp_f32 %0, %1" : "=v"(p) : "v"(arg));
          Pw[(mf * 16 + kg * 4 + r) * 64 + ((ct ^ kg) * 16 + rA)] = (f16)p;
        }

#pragma unroll
    for (int kc = 0; kc < 2; ++kc) {
      f16x8 vb[4];
#pragma unroll
      for (int dt = 0; dt < 4; ++dt)
        vb[dt] = *(const f16x8*)&Vc[(dt * 16 + rA) * 64 + (((kc * 4 + kg) ^ (rA & 7)) * 8)];
#pragma unroll
      for (int mf = 0; mf < 2; ++mf) {
        f16x8 pa = *(const f16x8*)&Pw[(mf * 16 + rA) * 64 + ((kc * 32 + kg * 8) ^ ((rA >> 2) << 4))];
#pragma unroll
        for (int dt = 0; dt < 4; ++dt)
          o[mf][dt] = MFMA16(pa, vb[dt], o[mf][dt]);
        osum[mf] = MFMA16(pa, vones, osum[mf]);
      }
    }
    if (tt + 2 < NS / 64) {
      __builtin_amdgcn_sched_barrier(0);
      __builtin_amdgcn_s_barrier();
      stage(cur, (tt + 2) * 64);
    }
  }

  float lrinv[2][4];
#pragma unroll
  for (int mf = 0; mf < 2; ++mf)
#pragma unroll
    for (int r = 0; r < 4; ++r) lrinv[mf][r] = 1.0f / osum[mf][r];
#pragma unroll
  for (int mf = 0; mf < 2; ++mf)
#pragma unroll
    for (int dt = 0; dt < 4; ++dt)
#pragma unroll
      for (int r = 0; r < 4; ++r) {
        size_t idx = (size_t)(b * NS + q0 + mf * 16 + kg * 4 + r) * HD + h * NDH + dt * 16 + rA;
        float v = o[mf][dt][r] * lrinv[mf][r] * (float)Rm[idx];
        outA[idx] = (f16)v;
      }
}

// ---------------------------------------------------------------------------
// Host launcher
// ---------------------------------------------------------------------------
extern "C" void kernel_launch(void* const* d_in, const int* in_sizes, int n_in,
                              void* d_out, int out_size, void* d_ws, size_t ws_size,
                              hipStream_t stream)
{
  const float* src  = (const float*)d_in[0];
  const float* ln1g = (const float*)d_in[2];
  const float* ln1b = (const float*)d_in[3];
  const float* Wq   = (const float*)d_in[4];
  const float* bq   = (const float*)d_in[5];
  const float* Wk   = (const float*)d_in[6];
  const float* bk   = (const float*)d_in[7];
  const float* Wv   = (const float*)d_in[8];
  const float* bv   = (const float*)d_in[9];
  const float* Wr   = (const float*)d_in[10];
  const float* br   = (const float*)d_in[11];
  const float* Wo   = (const float*)d_in[12];
  const float* bo   = (const float*)d_in[13];
  const float* ln2g = (const float*)d_in[14];
  const float* ln2b = (const float*)d_in[15];
  const float* W1   = (const float*)d_in[16];
  const float* b1   = (const float*)d_in[17];
  const float* W2   = (const float*)d_in[18];
  const float* b2   = (const float*)d_in[19];
  const float* ln3g = (const float*)d_in[20];
  const float* ln3b = (const float*)d_in[21];

  // ---- workspace layout -------------------------------------------------
  char* ws = (char*)d_ws;
  float* biasbuf = (float*)ws;
  size_t off = 40960 * sizeof(float);
  const size_t WT_L = 13631488;  // f16 elements per layer: 5*1M + 4M + 4M
  size_t act_bytes = (size_t)NM * 1024 * 20;
  bool upfront = ws_size >= off + 4 * WT_L * 2 + act_bytes;
  f16* wt = (f16*)(ws + off);
  off += (upfront ? 4 : 1) * WT_L * 2;
  float* xbuf = (float*)(ws + off); off += (size_t)NM * ND * 4;
  f16* mha    = (f16*)(ws + off);   off += (size_t)NM * ND * 4;  // f16 (half used)
  f16* zbuf   = (f16*)(ws + off);   off += (size_t)NM * ND * 2;
  f16* qkvr   = (f16*)(ws + off);   off += (size_t)NM * ND * 2 * 4;  // also h1
  f16* aout   = (f16*)(ws + off);

  pack_bias<<<160, 256, 0, stream>>>(bq, bk, bv, br, bo, b1, b2, biasbuf);

  if (upfront) {
    transpose_cvt<<<dim3(16, 16, 4), 256, 0, stream>>>(Wq, wt + 0,       1024, 1024, 1048576, (int)WT_L);
    transpose_cvt<<<dim3(16, 16, 4), 256, 0, stream>>>(Wk, wt + 1048576, 1024, 1024, 1048576, (int)WT_L);
    transpose_cvt<<<dim3(16, 16, 4), 256, 0, stream>>>(Wv, wt + 2097152, 1024, 1024, 1048576, (int)WT_L);
    transpose_cvt<<<dim3(16, 16, 4), 256, 0, stream>>>(Wr, wt + 3145728, 1024, 1024, 1048576, (int)WT_L);
    transpose_cvt<<<dim3(16, 16, 4), 256, 0, stream>>>(Wo, wt + 4194304, 1024, 1024, 1048576, (int)WT_L);
    transpose_cvt<<<dim3(64, 16, 4), 256, 0, stream>>>(W1, wt + 5242880, 1024, 4096, 4194304, (int)WT_L);
    transpose_cvt<<<dim3(16, 64, 4), 256, 0, stream>>>(W2, wt + 9437184, 4096, 1024, 4194304, (int)WT_L);
  }

  // LN1 for layer 0 (subsequent layers get it fused into LN3)
  ln_kernel<false, true><<<NM, 256, 0, stream>>>(src, ln1g, ln1b, zbuf);

  for (int l = 0; l < 4; ++l) {
    f16* wtL = upfront ? wt + (size_t)l * WT_L : wt;
    const float* bL = biasbuf + l * 10240;
    if (!upfront) {
      transpose_cvt<<<dim3(16, 16, 1), 256, 0, stream>>>(Wq + (size_t)l * 1048576, wt + 0,       1024, 1024, 0, 0);
      transpose_cvt<<<dim3(16, 16, 1), 256, 0, stream>>>(Wk + (size_t)l * 1048576, wt + 1048576, 1024, 1024, 0, 0);
      transpose_cvt<<<dim3(16, 16, 1), 256, 0, stream>>>(Wv + (size_t)l * 1048576, wt + 2097152, 1024, 1024, 0, 0);
      transpose_cvt<<<dim3(16, 16, 1), 256, 0, stream>>>(Wr + (size_t)l * 1048576, wt + 3145728, 1024, 1024, 0, 0);
      transpose_cvt<<<dim3(16, 16, 1), 256, 0, stream>>>(Wo + (size_t)l * 1048576, wt + 4194304, 1024, 1024, 0, 0);
      transpose_cvt<<<dim3(64, 16, 1), 256, 0, stream>>>(W1 + (size_t)l * 4194304, wt + 5242880, 1024, 4096, 0, 0);
      transpose_cvt<<<dim3(16, 64, 1), 256, 0, stream>>>(W2 + (size_t)l * 4194304, wt + 9437184, 4096, 1024, 0, 0);
    }
    const float* xin = l ? xbuf : src;

    // Q,K,Vt,R = z @ [Wq|Wk|Wv|Wr] + b  (unified N=4096; Q scaled by kC1;
    // V written transposed)
    gemm256<EPI_QKVR><<<dim3(16, 16), 512, 0, stream>>>(zbuf, wtL, bL, qkvr, 1024);
    // gated attention -> aout (f16)
    attn_kernel<<<dim3(512), 256, 0, stream>>>(
        qkvr, qkvr + 4194304, qkvr + 8388608, qkvr + 12582912, aout);
    // mha(f16) = x(f32) + aout @ Wo + bo
    gemm_bt<128, 64, 64><<<dim3(32, 16, 1), 256, 0, stream>>>(
        aout, wtL + 4194304, bL + 4096, xin, mha, nullptr, 1024, 1024, EPI_RESO16, 0, 0, 0);
    // z2 = LN2(mha)
    ln_kernel<true, true><<<NM, 256, 0, stream>>>(mha, ln2g + l * 1024, ln2b + l * 1024, zbuf);
    // h1 = relu(z2 @ W1 + b1)   (reuses QKVR buffer, N=4096)
    gemm256<EPI_RELU><<<dim3(16, 16), 512, 0, stream>>>(zbuf, wtL + 5242880, bL + 5120, qkvr, 1024);
    // mha(f16) = mha + h1 @ W2 + b2   (in-place residual)
    gemm_bt<128, 64, 64><<<dim3(32, 16, 1), 256, 0, stream>>>(
        qkvr, wtL + 9437184, bL + 9216, (const float*)mha, mha, nullptr, 1024, 4096, EPI_RESH16, 0, 0, 0);
    // LN3 (+ fused LN1 of next layer): y -> xbuf/d_out (f32), z -> zbuf (f16)
    if (l < 3)
      ln3ln1_kernel<false><<<NM, 256, 0, stream>>>(
          mha, ln3g + l * 1024, ln3b + l * 1024,
          ln1g + (l + 1) * 1024, ln1b + (l + 1) * 1024, xbuf, zbuf);
    else
      ln3ln1_kernel<true><<<NM, 256, 0, stream>>>(
          mha, ln3g + 3 * 1024, ln3b + 3 * 1024,
          nullptr, nullptr, (float*)d_out, nullptr);
  }
}

// Round 19
// 820.844 us; speedup vs baseline: 1.0801x; 1.0014x over previous
//
#include <hip/hip_runtime.h>

// ---------------------------------------------------------------------------
// Encoder: 4 layers of {LN1 -> QKVR proj -> role-gated attention -> Wo+res ->
// LN2 -> FFN(relu) + res -> LN3}.  B=4 S=1024 D=1024 H=16 DH=64 DF=4096.
// f32 I/O; internal GEMMs in fp16 MFMA (16x16x32) with f32 accumulate.
// N=4096 GEMMs (QKVR-unified, W1): 256x256xBK64 8-wave quadrant-phase kernel.
// N=1024 K-large GEMMs (Wo, W2): 128x64xBK64 3-buffer pipeline.
// R17: mha residual stream f16; LN3+LN1 fused.  R18: inter-layer residual
// y=LN3(mha) also f16 (layers 0-2; last layer writes f32 d_out).
// Attention: reduction-free softmax (clamped raw v_exp_f32 + ones-column
// MFMA denominator); C1 pre-folded into Q; 2-buffer KV, counted vmcnt.
// ---------------------------------------------------------------------------

typedef _Float16 f16;
typedef _Float16 f16x8 __attribute__((ext_vector_type(8)));
typedef _Float16 f16x4 __attribute__((ext_vector_type(4)));
typedef float    f32x4 __attribute__((ext_vector_type(4)));

#define GPTR(x) (const __attribute__((address_space(1))) void*)(x)
#define LPTR(x) (__attribute__((address_space(3))) void*)(x)
#define MFMA16(a,b,c) __builtin_amdgcn_mfma_f32_16x16x32_f16(a, b, c, 0, 0, 0)

static constexpr int NB   = 4;      // batch
static constexpr int NS   = 1024;   // seq
static constexpr int ND   = 1024;   // d_model
static constexpr int NH   = 16;     // heads
static constexpr int NDH  = 64;     // head dim
static constexpr int NDF  = 4096;   // ffn
static constexpr int NM   = NB * NS;        // 4096 rows
static constexpr int HD   = NH * NDH;       // 1024
static constexpr float kC1 = 0.180336879f;  // 0.125 * log2(e)

// epilogue modes
#define EPI_H      0   // outH[m*N+n] = acc + bias
#define EPI_VT     1   // outH[n*NM+m] = acc + bias   (V transposed)
#define EPI_RELU   2   // outH[m*N+n] = relu(acc + bias)
#define EPI_RESO16 3   // outH f16 = acc + bias + res(f32)
#define EPI_QKVR   4   // z==2 -> VT; z==0 scaled by kC1; else EPI_H
#define EPI_RESH16 5   // outH f16 = acc + bias + res(f16)  (in-place capable)

// ---------------------------------------------------------------------------
// Weight transpose + f32->f16 convert: src (R,C) row-major f32 -> dst (C,R) f16
// ---------------------------------------------------------------------------
__global__ __launch_bounds__(256) void transpose_cvt(
    const float* __restrict__ src, f16* __restrict__ dst,
    int R, int C, int srcZ, int dstZ)
{
  src += (size_t)blockIdx.z * srcZ;
  dst += (size_t)blockIdx.z * dstZ;
  __shared__ float tile[64][65];
  int t  = threadIdx.x;
  int c0 = blockIdx.x * 64, r0 = blockIdx.y * 64;
  int tr = t >> 4, tc4 = (t & 15) * 4;
#pragma unroll
  for (int i = 0; i < 4; ++i) {
    float4 v = *(const float4*)&src[(size_t)(r0 + tr + i * 16) * C + c0 + tc4];
    tile[tr + i * 16][tc4 + 0] = v.x;
    tile[tr + i * 16][tc4 + 1] = v.y;
    tile[tr + i * 16][tc4 + 2] = v.z;
    tile[tr + i * 16][tc4 + 3] = v.w;
  }
  __syncthreads();
  int n = t >> 2, ks = (t & 3) * 16;
  f16x8 o0, o1;
#pragma unroll
  for (int j = 0; j < 8; ++j) {
    o0[j] = (f16)tile[ks + j][n];
    o1[j] = (f16)tile[ks + 8 + j][n];
  }
  f16* dp = &dst[(size_t)(c0 + n) * R + r0 + ks];
  *(f16x8*)dp       = o0;
  *(f16x8*)(dp + 8) = o1;
}

// ---------------------------------------------------------------------------
// Pack the 7 bias arrays into one contiguous buffer.
// ---------------------------------------------------------------------------
__global__ __launch_bounds__(256) void pack_bias(
    const float* __restrict__ bq, const float* __restrict__ bk,
    const float* __restrict__ bv, const float* __restrict__ br,
    const float* __restrict__ bo, const float* __restrict__ b1,
    const float* __restrict__ b2, float* __restrict__ dst)
{
  int i = blockIdx.x * 256 + threadIdx.x;
  if (i >= 4 * 10240) return;
  int l = i / 10240, o = i % 10240;
  float v;
  if      (o < 1024) v = bq[l * 1024 + o];
  else if (o < 2048) v = bk[l * 1024 + o - 1024];
  else if (o < 3072) v = bv[l * 1024 + o - 2048];
  else if (o < 4096) v = br[l * 1024 + o - 3072];
  else if (o < 5120) v = bo[l * 1024 + o - 4096];
  else if (o < 9216) v = b1[l * 4096 + o - 5120];
  else               v = b2[l * 1024 + o - 9216];
  dst[i] = v;
}

// ---------------------------------------------------------------------------
// LayerNorm over D=1024: one row per block, 256 threads x 4 elements.
// F16IN: input f16 (mha stream); else f32.  F16OUT: f16 (GEMM operand).
// ---------------------------------------------------------------------------
template<bool F16IN, bool F16OUT>
__global__ __launch_bounds__(256) void ln_kernel(
    const void* __restrict__ in, const float* __restrict__ g,
    const float* __restrict__ b, void* __restrict__ out)
{
  int row = blockIdx.x, t = threadIdx.x;
  float x0, x1, x2, x3;
  if (F16IN) {
    f16x4 v = *(const f16x4*)((const f16*)in + (size_t)row * ND + t * 4);
    x0 = (float)v[0]; x1 = (float)v[1]; x2 = (float)v[2]; x3 = (float)v[3];
  } else {
    float4 v = *(const float4*)((const float*)in + (size_t)row * ND + t * 4);
    x0 = v.x; x1 = v.y; x2 = v.z; x3 = v.w;
  }
  float s  = x0 + x1 + x2 + x3;
  float sq = x0 * x0 + x1 * x1 + x2 * x2 + x3 * x3;
#pragma unroll
  for (int off = 32; off; off >>= 1) {
    s  += __shfl_xor(s, off, 64);
    sq += __shfl_xor(sq, off, 64);
  }
  __shared__ float rb[8];
  int wid = t >> 6;
  if ((t & 63) == 0) { rb[wid] = s; rb[4 + wid] = sq; }
  __syncthreads();
  s  = rb[0] + rb[1] + rb[2] + rb[3];
  sq = rb[4] + rb[5] + rb[6] + rb[7];
  float mean = s * (1.0f / ND);
  float var  = sq * (1.0f / ND) - mean * mean;
  float rstd = rsqrtf(var + 1e-5f);
  float4 g4 = *(const float4*)&g[t * 4];
  float4 b4 = *(const float4*)&b[t * 4];
  float o0 = (x0 - mean) * rstd * g4.x + b4.x;
  float o1 = (x1 - mean) * rstd * g4.y + b4.y;
  float o2 = (x2 - mean) * rstd * g4.z + b4.z;
  float o3 = (x3 - mean) * rstd * g4.w + b4.w;
  if (F16OUT) {
    f16x4 ov = { (f16)o0, (f16)o1, (f16)o2, (f16)o3 };
    *(f16x4*)((f16*)out + (size_t)row * ND + t * 4) = ov;
  } else {
    float4 ov = { o0, o1, o2, o3 };
    *(float4*)((float*)out + (size_t)row * ND + t * 4) = ov;
  }
}

// ---------------------------------------------------------------------------
// Fused LN3 -> LN1(next layer).  in = mha2 (f16).
// !LAST: y = LN3(in) written f16 (next layer's residual); z = LN1(y) f16.
//  LAST: y written f32 to d_out only.
// ---------------------------------------------------------------------------
template<bool LAST>
__global__ __launch_bounds__(256) void ln3ln1_kernel(
    const f16* __restrict__ in, const float* __restrict__ g3,
    const float* __restrict__ b3, const float* __restrict__ g1,
    const float* __restrict__ b1, void* __restrict__ yout,
    f16* __restrict__ zout)
{
  int row = blockIdx.x, t = threadIdx.x;
  f16x4 v = *(const f16x4*)&in[(size_t)row * ND + t * 4];
  float x0 = (float)v[0], x1 = (float)v[1], x2 = (float)v[2], x3 = (float)v[3];
  float s  = x0 + x1 + x2 + x3;
  float sq = x0 * x0 + x1 * x1 + x2 * x2 + x3 * x3;
#pragma unroll
  for (int off = 32; off; off >>= 1) {
    s  += __shfl_xor(s, off, 64);
    sq += __shfl_xor(sq, off, 64);
  }
  __shared__ float rb[16];
  int wid = t >> 6;
  if ((t & 63) == 0) { rb[wid] = s; rb[4 + wid] = sq; }
  __syncthreads();
  s  = rb[0] + rb[1] + rb[2] + rb[3];
  sq = rb[4] + rb[5] + rb[6] + rb[7];
  float mean = s * (1.0f / ND);
  float var  = sq * (1.0f / ND) - mean * mean;
  float rstd = rsqrtf(var + 1e-5f);
  float4 g4 = *(const float4*)&g3[t * 4];
  float4 b4 = *(const float4*)&b3[t * 4];
  float y0 = (x0 - mean) * rstd * g4.x + b4.x;
  float y1 = (x1 - mean) * rstd * g4.y + b4.y;
  float y2 = (x2 - mean) * rstd * g4.z + b4.z;
  float y3 = (x3 - mean) * rstd * g4.w + b4.w;
  if (LAST) {
    float4 yv = { y0, y1, y2, y3 };
    *(float4*)((float*)yout + (size_t)row * ND + t * 4) = yv;
  } else {
    f16x4 yv = { (f16)y0, (f16)y1, (f16)y2, (f16)y3 };
    *(f16x4*)((f16*)yout + (size_t)row * ND + t * 4) = yv;
    float s2  = y0 + y1 + y2 + y3;
    float q2  = y0 * y0 + y1 * y1 + y2 * y2 + y3 * y3;
#pragma unroll
    for (int off = 32; off; off >>= 1) {
      s2 += __shfl_xor(s2, off, 64);
      q2 += __shfl_xor(q2, off, 64);
    }
    if ((t & 63) == 0) { rb[8 + wid] = s2; rb[12 + wid] = q2; }
    __syncthreads();
    s2 = rb[8] + rb[9] + rb[10] + rb[11];
    q2 = rb[12] + rb[13] + rb[14] + rb[15];
    float mean2 = s2 * (1.0f / ND);
    float var2  = q2 * (1.0f / ND) - mean2 * mean2;
    float rstd2 = rsqrtf(var2 + 1e-5f);
    float4 g14 = *(const float4*)&g1[t * 4];
    float4 b14 = *(const float4*)&b1[t * 4];
    f16x4 zv = { (f16)((y0 - mean2) * rstd2 * g14.x + b14.x),
                 (f16)((y1 - mean2) * rstd2 * g14.y + b14.y),
                 (f16)((y2 - mean2) * rstd2 * g14.z + b14.z),
                 (f16)((y3 - mean2) * rstd2 * g14.w + b14.w) };
    *(f16x4*)&zout[(size_t)row * ND + t * 4] = zv;
  }
}

// ---------------------------------------------------------------------------
// gemm256: C(4096 x 4096) = A(4096 x K) * Bt(4096 x K)^T + bias, f16 out.
// 256x256xBK64, 512 threads = 8 waves; quadrant-phase K-loop (best-measured).
// EPI_QKVR: z==2 writes V^T; z==0 (Q) scaled by kC1.
// ---------------------------------------------------------------------------
template<int EPIMODE>
__global__ __launch_bounds__(512, 2) void gemm256(
    const f16* __restrict__ A, const f16* __restrict__ Bt,
    const float* __restrict__ bias, f16* __restrict__ outH, int K)
{
  constexpr int BM = 256, BN = 256, BK = 64;
  constexpr int ASZ = BM * BK;
  constexpr int TSZ = 2 * ASZ;
  __shared__ f16 sm[2 * TSZ];

  int lin = blockIdx.x + (blockIdx.y << 4);
  int l2  = (lin & 7) * 32 + (lin >> 3);
  int by  = l2 & 15, bx = l2 >> 4;

  int t = threadIdx.x;
  int wid = t >> 6, lane = t & 63;
  int wr = wid >> 2, wc = wid & 3;
  int rA = lane & 15, kg = lane >> 4;
  int m0 = bx * BM, n0 = by * BN;

  f32x4 acc[8][4] = {};
  const f16* Abase = A  + (size_t)m0 * K;
  const f16* Bbase = Bt + (size_t)n0 * K;

  auto stage = [&](int buf, int kt) {
    f16* As = sm + buf * TSZ;
    f16* Bs = As + ASZ;
#pragma unroll
    for (int i = 0; i < 4; ++i) {
      int p = i * 512 + t;
      int row = p >> 3, c = (p & 7) ^ (row & 7);
      __builtin_amdgcn_global_load_lds(
          GPTR(Abase + (size_t)row * K + kt + c * 8),
          LPTR(As + (i * 512 + wid * 64) * 8), 16, 0, 0);
    }
#pragma unroll
    for (int i = 0; i < 4; ++i) {
      int p = i * 512 + t;
      int row = p >> 3, c = (p & 7) ^ (row & 7);
      __builtin_amdgcn_global_load_lds(
          GPTR(Bbase + (size_t)row * K + kt + c * 8),
          LPTR(Bs + (i * 512 + wid * 64) * 8), 16, 0, 0);
    }
  };

  int nIt = K / BK;                    // 16
  stage(0, 0);
  stage(1, BK);
  for (int it = 0; it < nIt; ++it) {
    int cur = it & 1;
    if (it + 1 < nIt) {
      asm volatile("s_waitcnt vmcnt(8)" ::: "memory");
    } else {
      asm volatile("s_waitcnt vmcnt(0)" ::: "memory");
    }
    __builtin_amdgcn_s_barrier();
    __builtin_amdgcn_sched_barrier(0);
    const f16* As = sm + cur * TSZ;
    const f16* Bs = As + ASZ;
    f16x8 af[8][2], bf[4][2];

    // ---- phase 0: (m0-3, n0-1); reads af[0..3], bf[0..1] ----------------
#pragma unroll
    for (int m = 0; m < 4; ++m) {
      int r = wr * 128 + m * 16 + rA;
#pragma unroll
      for (int h = 0; h < 2; ++h)
        af[m][h] = *(const f16x8*)&As[r * BK + (((h * 4 + kg) ^ (r & 7)) * 8)];
    }
#pragma unroll
    for (int n = 0; n < 2; ++n) {
      int r = wc * 64 + n * 16 + rA;
#pragma unroll
      for (int h = 0; h < 2; ++h)
        bf[n][h] = *(const f16x8*)&Bs[r * BK + (((h * 4 + kg) ^ (r & 7)) * 8)];
    }
    asm volatile("s_waitcnt lgkmcnt(0)" ::: "memory");
    __builtin_amdgcn_sched_barrier(0);
    __builtin_amdgcn_s_setprio(1);
#pragma unroll
    for (int h = 0; h < 2; ++h)
#pragma unroll
      for (int m = 0; m < 4; ++m)
#pragma unroll
        for (int n = 0; n < 2; ++n)
          acc[m][n] = MFMA16(af[m][h], bf[n][h], acc[m][n]);
    __builtin_amdgcn_s_setprio(0);
    __builtin_amdgcn_sched_barrier(0);
    __builtin_amdgcn_s_barrier();

    // ---- phase 1: (m0-3, n2-3); reads bf[2..3] --------------------------
#pragma unroll
    for (int n = 2; n < 4; ++n) {
      int r = wc * 64 + n * 16 + rA;
#pragma unroll
      for (int h = 0; h < 2; ++h)
        bf[n][h] = *(const f16x8*)&Bs[r * BK + (((h * 4 + kg) ^ (r & 7)) * 8)];
    }
    asm volatile("s_waitcnt lgkmcnt(0)" ::: "memory");
    __builtin_amdgcn_sched_barrier(0);
    __builtin_amdgcn_s_setprio(1);
#pragma unroll
    for (int h = 0; h < 2; ++h)
#pragma unroll
      for (int m = 0; m < 4; ++m)
#pragma unroll
        for (int n = 2; n < 4; ++n)
          acc[m][n] = MFMA16(af[m][h], bf[n][h], acc[m][n]);
    __builtin_amdgcn_s_setprio(0);
    __builtin_amdgcn_sched_barrier(0);
    __builtin_amdgcn_s_barrier();

    // ---- phase 2: (m4-7, n0-1); reads af[4..7] --------------------------
#pragma unroll
    for (int m = 4; m < 8; ++m) {
      int r = wr * 128 + m * 16 + rA;
#pragma unroll
      for (int h = 0; h < 2; ++h)
        af[m][h] = *(const f16x8*)&As[r * BK + (((h * 4 + kg) ^ (r & 7)) * 8)];
    }
    asm volatile("s_waitcnt lgkmcnt(0)" ::: "memory");
    __builtin_amdgcn_sched_barrier(0);
    __builtin_amdgcn_s_setprio(1);
#pragma unroll
    for (int h = 0; h < 2; ++h)
#pragma unroll
      for (int m = 4; m < 8; ++m)
#pragma unroll
        for (int n = 0; n < 2; ++n)
          acc[m][n] = MFMA16(af[m][h], bf[n][h], acc[m][n]);
    __builtin_amdgcn_s_setprio(0);
    __builtin_amdgcn_sched_barrier(0);
    __builtin_amdgcn_s_barrier();

    // ---- phase 3: (m4-7, n2-3); no reads -> issue next-next stage -------
    if (it + 2 < nIt) stage(cur, (it + 2) * BK);
    __builtin_amdgcn_s_setprio(1);
#pragma unroll
    for (int h = 0; h < 2; ++h)
#pragma unroll
      for (int m = 4; m < 8; ++m)
#pragma unroll
        for (int n = 2; n < 4; ++n)
          acc[m][n] = MFMA16(af[m][h], bf[n][h], acc[m][n]);
    __builtin_amdgcn_s_setprio(0);
    __builtin_amdgcn_sched_barrier(0);
  }

  // ---- epilogue (fragment: C row = kg*4 + r, col = rA) -------------------
  __builtin_amdgcn_s_barrier();
  if (EPIMODE == EPI_QKVR && (n0 >> 10) == 2) {
    f16* vt = outH + (size_t)2 * 4194304;
#pragma unroll
    for (int n = 0; n < 4; ++n) {
      int gn = n0 + wc * 64 + n * 16 + rA;
      int gnl = gn & 1023;
      float bvv = bias[gn];
#pragma unroll
      for (int m = 0; m < 8; ++m) {
        int gmb = m0 + wr * 128 + m * 16 + kg * 4;
        f16x4 ov = { (f16)(acc[m][n][0] + bvv), (f16)(acc[m][n][1] + bvv),
                     (f16)(acc[m][n][2] + bvv), (f16)(acc[m][n][3] + bvv) };
        *(f16x4*)&vt[(size_t)gnl * NM + gmb] = ov;
      }
    }
  } else {
    bool scaleQ = (EPIMODE == EPI_QKVR) && ((n0 >> 10) == 0);
#pragma unroll
    for (int n = 0; n < 4; ++n) {
      int cl = wc * 64 + n * 16 + rA;
      float bvv = bias[n0 + cl];
#pragma unroll
      for (int m = 0; m < 8; ++m) {
        int rl = wr * 128 + m * 16 + kg * 4;
#pragma unroll
        for (int r = 0; r < 4; ++r) {
          float v = acc[m][n][r] + bvv;
          if (EPIMODE == EPI_RELU) v = fmaxf(v, 0.0f);
          if (scaleQ) v *= kC1;
          sm[(rl + r) * 256 + cl] = (f16)v;
        }
      }
    }
    __syncthreads();
    f16* outp;
    int ldo, col0;
    if (EPIMODE == EPI_QKVR) {
      int z = n0 >> 10;
      outp = outH + (size_t)z * 4194304; ldo = 1024; col0 = n0 & 1023;
    } else {
      outp = outH; ldo = 4096; col0 = n0;
    }
#pragma unroll
    for (int i = 0; i < 16; ++i) {
      int p = i * 512 + t;
      int row = p >> 5, c8 = p & 31;
      *(f16x8*)&outp[(size_t)(m0 + row) * ldo + col0 + c8 * 8] =
          *(const f16x8*)&sm[row * 256 + c8 * 8];
    }
  }
}

// ---------------------------------------------------------------------------
// GEMM: C(M x N) = A(M x K) * Bt(N x K)^T + bias (+ residual / relu / VT).
// 3-buffer counted-vmcnt pipeline.  Used for Wo (EPI_RESO16 layer 0 /
// EPI_RESH16 layers 1-3) and W2 (EPI_RESH16 in-place).
// ---------------------------------------------------------------------------
template<int BM, int BN, int BK>
__global__ __launch_bounds__(256) void gemm_bt(
    const f16* __restrict__ A, const f16* __restrict__ Bt,
    const float* __restrict__ bias, const float* __restrict__ res,
    f16* __restrict__ outH, float* __restrict__ outF,
    int N, int K, int epi, int zBt, int zBias, int zOut)
{
  constexpr int CH = BK / 8;
  constexpr int CM = CH - 1;
  constexpr int KH = BK / 32;
  constexpr int FM = BM / 32, FN = BN / 32;
  constexpr int ASZ = BM * BK, BSZ = BN * BK;
  constexpr int TSZ = ASZ + BSZ;
  constexpr int LPT = (BM + BN) * CH / 256;
  constexpr int SMEM = (3 * TSZ > BM * BN) ? 3 * TSZ : BM * BN;
  __shared__ f16 sm[SMEM];

  auto SWZ = [](int row) { return ((CH == 4) ? (row >> 1) : row) & CM; };

  int nx = gridDim.x, ny = gridDim.y;
  int lin = blockIdx.x + nx * (blockIdx.y + ny * blockIdx.z);
  int tot = nx * ny * gridDim.z;
  int l2  = (lin & 7) * (tot >> 3) + (lin >> 3);
  int by  = l2 % ny; int rem = l2 / ny; int bx = rem % nx; int z = rem / nx;

  Bt += (size_t)z * zBt;
  const float* biasz = bias + (size_t)z * zBias;
  int ep = (epi == EPI_QKVR) ? ((z == 2) ? EPI_VT : EPI_H) : epi;

  int t = threadIdx.x;
  int wid = t >> 6, lane = t & 63;
  int wr = wid >> 1, wc = wid & 1;
  int rA = lane & 15, kg = lane >> 4;
  int m0 = bx * BM, n0 = by * BN;

  f32x4 acc[FM][FN] = {};
  const f16* Abase = A  + (size_t)m0 * K;
  const f16* Bbase = Bt + (size_t)n0 * K;

  auto stage = [&](int buf, int kt) {
    f16* As = sm + buf * TSZ;
    f16* Bs = As + ASZ;
#pragma unroll
    for (int i = 0; i < BM * CH / 256; ++i) {
      int p = i * 256 + t;
      int row = p / CH, c = (p & CM) ^ SWZ(row);
      __builtin_amdgcn_global_load_lds(
          GPTR(Abase + (size_t)row * K + kt + c * 8),
          LPTR(As + (i * 256 + wid * 64) * 8), 16, 0, 0);
    }
#pragma unroll
    for (int i = 0; i < BN * CH / 256; ++i) {
      int p = i * 256 + t;
      int row = p / CH, c = (p & CM) ^ SWZ(row);
      __builtin_amdgcn_global_load_lds(
          GPTR(Bbase + (size_t)row * K + kt + c * 8),
          LPTR(Bs + (i * 256 + wid * 64) * 8), 16, 0, 0);
    }
  };

  int nIt = K / BK;
  stage(0, 0);
  if (nIt > 1) stage(1, BK);
  int cur = 0, nxt = 2;
  for (int it = 0; it < nIt; ++it) {
    if (it + 1 < nIt) {
      asm volatile("s_waitcnt vmcnt(%0)" :: "n"(LPT) : "memory");
    } else {
      asm volatile("s_waitcnt vmcnt(0)" ::: "memory");
    }
    __builtin_amdgcn_s_barrier();
    __builtin_amdgcn_sched_barrier(0);
    if (it + 2 < nIt) stage(nxt, (it + 2) * BK);
    const f16* As = sm + cur * TSZ;
    const f16* Bs = As + ASZ;
    f16x8 af[FM][KH], bf[FN][KH];
#pragma unroll
    for (int m = 0; m < FM; ++m) {
      int r = wr * (BM / 2) + m * 16 + rA;
#pragma unroll
      for (int h = 0; h < KH; ++h)
        af[m][h] = *(const f16x8*)&As[r * BK + (((h * 4 + kg) ^ SWZ(r)) * 8)];
    }
#pragma unroll
    for (int n = 0; n < FN; ++n) {
      int r = wc * (BN / 2) + n * 16 + rA;
#pragma unroll
      for (int h = 0; h < KH; ++h)
        bf[n][h] = *(const f16x8*)&Bs[r * BK + (((h * 4 + kg) ^ SWZ(r)) * 8)];
    }
#pragma unroll
    for (int h = 0; h < KH; ++h)
#pragma unroll
      for (int m = 0; m < FM; ++m)
#pragma unroll
        for (int n = 0; n < FN; ++n)
          acc[m][n] = MFMA16(af[m][h], bf[n][h], acc[m][n]);
    cur = (cur == 2) ? 0 : cur + 1;
    nxt = (nxt == 2) ? 0 : nxt + 1;
  }

  // ---- epilogue (fragment: C row = kg*4 + r, col = rA) -------------------
  if (ep == EPI_VT) {
#pragma unroll
    for (int n = 0; n < FN; ++n) {
      int gn = n0 + wc * (BN / 2) + n * 16 + rA;
      float bvv = biasz[gn];
#pragma unroll
      for (int m = 0; m < FM; ++m) {
        int gmb = m0 + wr * (BM / 2) + m * 16 + kg * 4;
        f16x4 ov = { (f16)(acc[m][n][0] + bvv), (f16)(acc[m][n][1] + bvv),
                     (f16)(acc[m][n][2] + bvv), (f16)(acc[m][n][3] + bvv) };
        *(f16x4*)&outH[(size_t)z * zOut + (size_t)gn * NM + gmb] = ov;
      }
    }
  } else {
    // LDS-staged coalesced f16 writeout (with optional residual add)
    __builtin_amdgcn_sched_barrier(0);
    __builtin_amdgcn_s_barrier();   // all waves done reading sm
#pragma unroll
    for (int n = 0; n < FN; ++n) {
      int cl = wc * (BN / 2) + n * 16 + rA;
      float bvv = biasz[n0 + cl];
#pragma unroll
      for (int m = 0; m < FM; ++m) {
        int rl = wr * (BM / 2) + m * 16 + kg * 4;
#pragma unroll
        for (int r = 0; r < 4; ++r) {
          float v = acc[m][n][r] + bvv;
          if (ep == EPI_RELU) v = fmaxf(v, 0.0f);
          sm[(rl + r) * BN + cl] = (f16)v;
        }
      }
    }
    __syncthreads();
    f16* outp = outH + (size_t)z * zOut;
#pragma unroll
    for (int i = 0; i < BM * BN / 2048; ++i) {
      int p = i * 256 + t;
      int row = p / (BN / 8), c8 = p % (BN / 8);
      size_t gidx = (size_t)(m0 + row) * N + n0 + c8 * 8;
      f16x8 sv = *(const f16x8*)&sm[row * BN + c8 * 8];
      if (ep == EPI_RESO16) {
        const float* rp = res + gidx;
        float4 ra = *(const float4*)rp;
        float4 rc = *(const float4*)(rp + 4);
        f16x8 ov;
        ov[0] = (f16)((float)sv[0] + ra.x);
        ov[1] = (f16)((float)sv[1] + ra.y);
        ov[2] = (f16)((float)sv[2] + ra.z);
        ov[3] = (f16)((float)sv[3] + ra.w);
        ov[4] = (f16)((float)sv[4] + rc.x);
        ov[5] = (f16)((float)sv[5] + rc.y);
        ov[6] = (f16)((float)sv[6] + rc.z);
        ov[7] = (f16)((float)sv[7] + rc.w);
        *(f16x8*)&outp[gidx] = ov;
      } else if (ep == EPI_RESH16) {
        const f16* rh = (const f16*)res;
        f16x8 rv = *(const f16x8*)&rh[gidx];
        f16x8 ov;
#pragma unroll
        for (int j = 0; j < 8; ++j)
          ov[j] = (f16)((float)sv[j] + (float)rv[j]);
        *(f16x8*)&outp[gidx] = ov;
      } else {
        *(f16x8*)&outp[gidx] = sv;
      }
    }
  }
}

// ---------------------------------------------------------------------------
// Role-gated flash attention.  grid 512, 256 threads = 4 waves, 32 q/wave.
// 2-buffer KV (48 KB LDS -> 3 blocks/CU), double-barrier counted-vmcnt.
// Softmax reduction-free: Q pre-scaled by kC1, P = v_exp_f32(min(sc,14.5));
// denominator = P @ ones via MFMA.
// ---------------------------------------------------------------------------
__global__ __launch_bounds__(256) void attn_kernel(
    const f16* __restrict__ Qm, const f16* __restrict__ Km,
    const f16* __restrict__ Vt, const f16* __restrict__ Rm,
    f16* __restrict__ outA)
{
  int t = threadIdx.x, wid = t >> 6, lane = t & 63;
  int rA = lane & 15, kg = lane >> 4;
  int id = blockIdx.x;
  int j = id >> 3;
  int bh = (id & 7) * 8 + (j & 7), qb = j >> 3;   // XCD-contiguous per head
  int b = bh >> 4, h = bh & 15;
  int q0 = qb * 128 + wid * 32;

  __shared__ f16 KVs[2][2 * 64 * 64];   // 32 KB
  __shared__ f16 P[4][32 * 64];         // 16 KB
  f16* Pw = P[wid];

  f16x8 aq[2][2];
#pragma unroll
  for (int mf = 0; mf < 2; ++mf) {
    size_t qoff = (size_t)(b * NS + q0 + mf * 16 + rA) * HD + h * NDH + kg * 8;
    aq[mf][0] = *(const f16x8*)&Qm[qoff];
    aq[mf][1] = *(const f16x8*)&Qm[qoff + 32];
  }

  f32x4 o[2][4] = {};
  f32x4 osum[2] = {};
  f16x8 vones;
#pragma unroll
  for (int jj = 0; jj < 8; ++jj) vones[jj] = (f16)1.0f;

  auto stage = [&](int buf, int kv) {
    f16* Ks = KVs[buf];
    f16* Vs = Ks + 64 * 64;
#pragma unroll
    for (int i = 0; i < 2; ++i) {
      int p = i * 256 + t;
      int row = p >> 3, c16 = (p & 7) ^ (row & 7);
      __builtin_amdgcn_global_load_lds(
          GPTR(Km + (size_t)(b * NS + kv + row) * HD + h * NDH + c16 * 8),
          LPTR(Ks + (i * 256 + wid * 64) * 8), 16, 0, 0);
    }
#pragma unroll
    for (int i = 0; i < 2; ++i) {
      int p = i * 256 + t;
      int row = p >> 3, c16 = (p & 7) ^ (row & 7);
      __builtin_amdgcn_global_load_lds(
          GPTR(Vt + (size_t)(h * NDH + row) * NM + b * NS + kv + c16 * 8),
          LPTR(Vs + (i * 256 + wid * 64) * 8), 16, 0, 0);
    }
  };

  stage(0, 0);
  stage(1, 64);
  for (int tt = 0; tt < NS / 64; ++tt) {
    int cur = tt & 1;
    if (tt + 1 < NS / 64) {
      asm volatile("s_waitcnt vmcnt(4)" ::: "memory");
    } else {
      asm volatile("s_waitcnt vmcnt(0)" ::: "memory");
    }
    __builtin_amdgcn_s_barrier();
    __builtin_amdgcn_sched_barrier(0);
    const f16* Kc = KVs[cur];
    const f16* Vc = Kc + 64 * 64;

    f32x4 sc[2][4];
#pragma unroll
    for (int ct = 0; ct < 4; ++ct) {
      int krow = ct * 16 + rA;
      f16x8 kb0 = *(const f16x8*)&Kc[krow * 64 + ((kg ^ (rA & 7)) * 8)];
      f16x8 kb1 = *(const f16x8*)&Kc[krow * 64 + (((4 + kg) ^ (rA & 7)) * 8)];
#pragma unroll
      for (int mf = 0; mf < 2; ++mf) {
        f32x4 a = {};
        a = MFMA16(aq[mf][0], kb0, a);
        a = MFMA16(aq[mf][1], kb1, a);
        sc[mf][ct] = a;
      }
    }

#pragma unroll
    for (int mf = 0; mf < 2; ++mf)
#pragma unroll
      for (int ct = 0; ct < 4; ++ct)
#pragma unroll
        for (int r = 0; r < 4; ++r) {
          float arg = fminf(sc[mf][ct][r], 14.5f);
          float p;
          asm("v_exp_f32 %0, %1" : "=v"(p) : "v"(arg));
          Pw[(mf * 16 + kg * 4 + r) * 64 + ((ct ^ kg) * 16 + rA)] = (f16)p;
        }

#pragma unroll
    for (int kc = 0; kc < 2; ++kc) {
      f16x8 vb[4];
#pragma unroll
      for (int dt = 0; dt < 4; ++dt)
        vb[dt] = *(const f16x8*)&Vc[(dt * 16 + rA) * 64 + (((kc * 4 + kg) ^ (rA & 7)) * 8)];
#pragma unroll
      for (int mf = 0; mf < 2; ++mf) {
        f16x8 pa = *(const f16x8*)&Pw[(mf * 16 + rA) * 64 + ((kc * 32 + kg * 8) ^ ((rA >> 2) << 4))];
#pragma unroll
        for (int dt = 0; dt < 4; ++dt)
          o[mf][dt] = MFMA16(pa, vb[dt], o[mf][dt]);
        osum[mf] = MFMA16(pa, vones, osum[mf]);
      }
    }
    if (tt + 2 < NS / 64) {
      __builtin_amdgcn_sched_barrier(0);
      __builtin_amdgcn_s_barrier();
      stage(cur, (tt + 2) * 64);
    }
  }

  float lrinv[2][4];
#pragma unroll
  for (int mf = 0; mf < 2; ++mf)
#pragma unroll
    for (int r = 0; r < 4; ++r) lrinv[mf][r] = 1.0f / osum[mf][r];
#pragma unroll
  for (int mf = 0; mf < 2; ++mf)
#pragma unroll
    for (int dt = 0; dt < 4; ++dt)
#pragma unroll
      for (int r = 0; r < 4; ++r) {
        size_t idx = (size_t)(b * NS + q0 + mf * 16 + kg * 4 + r) * HD + h * NDH + dt * 16 + rA;
        float v = o[mf][dt][r] * lrinv[mf][r] * (float)Rm[idx];
        outA[idx] = (f16)v;
      }
}

// ---------------------------------------------------------------------------
// Host launcher
// ---------------------------------------------------------------------------
extern "C" void kernel_launch(void* const* d_in, const int* in_sizes, int n_in,
                              void* d_out, int out_size, void* d_ws, size_t ws_size,
                              hipStream_t stream)
{
  const float* src  = (const float*)d_in[0];
  const float* ln1g = (const float*)d_in[2];
  const float* ln1b = (const float*)d_in[3];
  const float* Wq   = (const float*)d_in[4];
  const float* bq   = (const float*)d_in[5];
  const float* Wk   = (const float*)d_in[6];
  const float* bk   = (const float*)d_in[7];
  const float* Wv   = (const float*)d_in[8];
  const float* bv   = (const float*)d_in[9];
  const float* Wr   = (const float*)d_in[10];
  const float* br   = (const float*)d_in[11];
  const float* Wo   = (const float*)d_in[12];
  const float* bo   = (const float*)d_in[13];
  const float* ln2g = (const float*)d_in[14];
  const float* ln2b = (const float*)d_in[15];
  const float* W1   = (const float*)d_in[16];
  const float* b1   = (const float*)d_in[17];
  const float* W2   = (const float*)d_in[18];
  const float* b2   = (const float*)d_in[19];
  const float* ln3g = (const float*)d_in[20];
  const float* ln3b = (const float*)d_in[21];

  // ---- workspace layout -------------------------------------------------
  char* ws = (char*)d_ws;
  float* biasbuf = (float*)ws;
  size_t off = 40960 * sizeof(float);
  const size_t WT_L = 13631488;  // f16 elements per layer: 5*1M + 4M + 4M
  size_t act_bytes = (size_t)NM * 1024 * 20;
  bool upfront = ws_size >= off + 4 * WT_L * 2 + act_bytes;
  f16* wt = (f16*)(ws + off);
  off += (upfront ? 4 : 1) * WT_L * 2;
  f16* xbuf16 = (f16*)(ws + off);   off += (size_t)NM * ND * 4;  // f16 (half used)
  f16* mha    = (f16*)(ws + off);   off += (size_t)NM * ND * 4;  // f16 (half used)
  f16* zbuf   = (f16*)(ws + off);   off += (size_t)NM * ND * 2;
  f16* qkvr   = (f16*)(ws + off);   off += (size_t)NM * ND * 2 * 4;  // also h1
  f16* aout   = (f16*)(ws + off);

  pack_bias<<<160, 256, 0, stream>>>(bq, bk, bv, br, bo, b1, b2, biasbuf);

  if (upfront) {
    transpose_cvt<<<dim3(16, 16, 4), 256, 0, stream>>>(Wq, wt + 0,       1024, 1024, 1048576, (int)WT_L);
    transpose_cvt<<<dim3(16, 16, 4), 256, 0, stream>>>(Wk, wt + 1048576, 1024, 1024, 1048576, (int)WT_L);
    transpose_cvt<<<dim3(16, 16, 4), 256, 0, stream>>>(Wv, wt + 2097152, 1024, 1024, 1048576, (int)WT_L);
    transpose_cvt<<<dim3(16, 16, 4), 256, 0, stream>>>(Wr, wt + 3145728, 1024, 1024, 1048576, (int)WT_L);
    transpose_cvt<<<dim3(16, 16, 4), 256, 0, stream>>>(Wo, wt + 4194304, 1024, 1024, 1048576, (int)WT_L);
    transpose_cvt<<<dim3(64, 16, 4), 256, 0, stream>>>(W1, wt + 5242880, 1024, 4096, 4194304, (int)WT_L);
    transpose_cvt<<<dim3(16, 64, 4), 256, 0, stream>>>(W2, wt + 9437184, 4096, 1024, 4194304, (int)WT_L);
  }

  // LN1 for layer 0 (subsequent layers get it fused into LN3)
  ln_kernel<false, true><<<NM, 256, 0, stream>>>(src, ln1g, ln1b, zbuf);

  for (int l = 0; l < 4; ++l) {
    f16* wtL = upfront ? wt + (size_t)l * WT_L : wt;
    const float* bL = biasbuf + l * 10240;
    if (!upfront) {
      transpose_cvt<<<dim3(16, 16, 1), 256, 0, stream>>>(Wq + (size_t)l * 1048576, wt + 0,       1024, 1024, 0, 0);
      transpose_cvt<<<dim3(16, 16, 1), 256, 0, stream>>>(Wk + (size_t)l * 1048576, wt + 1048576, 1024, 1024, 0, 0);
      transpose_cvt<<<dim3(16, 16, 1), 256, 0, stream>>>(Wv + (size_t)l * 1048576, wt + 2097152, 1024, 1024, 0, 0);
      transpose_cvt<<<dim3(16, 16, 1), 256, 0, stream>>>(Wr + (size_t)l * 1048576, wt + 3145728, 1024, 1024, 0, 0);
      transpose_cvt<<<dim3(16, 16, 1), 256, 0, stream>>>(Wo + (size_t)l * 1048576, wt + 4194304, 1024, 1024, 0, 0);
      transpose_cvt<<<dim3(64, 16, 1), 256, 0, stream>>>(W1 + (size_t)l * 4194304, wt + 5242880, 1024, 4096, 0, 0);
      transpose_cvt<<<dim3(16, 64, 1), 256, 0, stream>>>(W2 + (size_t)l * 4194304, wt + 9437184, 4096, 1024, 0, 0);
    }

    // Q,K,Vt,R = z @ [Wq|Wk|Wv|Wr] + b  (unified N=4096; Q scaled by kC1;
    // V written transposed)
    gemm256<EPI_QKVR><<<dim3(16, 16), 512, 0, stream>>>(zbuf, wtL, bL, qkvr, 1024);
    // gated attention -> aout (f16)
    attn_kernel<<<dim3(512), 256, 0, stream>>>(
        qkvr, qkvr + 4194304, qkvr + 8388608, qkvr + 12582912, aout);
    // mha(f16) = x + aout @ Wo + bo   (x: f32 src for l==0, f16 xbuf16 after)
    gemm_bt<128, 64, 64><<<dim3(32, 16, 1), 256, 0, stream>>>(
        aout, wtL + 4194304, bL + 4096,
        l ? (const float*)xbuf16 : src, mha, nullptr,
        1024, 1024, l ? EPI_RESH16 : EPI_RESO16, 0, 0, 0);
    // z2 = LN2(mha)
    ln_kernel<true, true><<<NM, 256, 0, stream>>>(mha, ln2g + l * 1024, ln2b + l * 1024, zbuf);
    // h1 = relu(z2 @ W1 + b1)   (reuses QKVR buffer, N=4096)
    gemm256<EPI_RELU><<<dim3(16, 16), 512, 0, stream>>>(zbuf, wtL + 5242880, bL + 5120, qkvr, 1024);
    // mha(f16) = mha + h1 @ W2 + b2   (in-place residual)
    gemm_bt<128, 64, 64><<<dim3(32, 16, 1), 256, 0, stream>>>(
        qkvr, wtL + 9437184, bL + 9216, (const float*)mha, mha, nullptr, 1024, 4096, EPI_RESH16, 0, 0, 0);
    // LN3 (+ fused LN1 of next layer): y -> xbuf16 (f16) / d_out (f32 LAST)
    if (l < 3)
      ln3ln1_kernel<false><<<NM, 256, 0, stream>>>(
          mha, ln3g + l * 1024, ln3b + l * 1024,
          ln1g + (l + 1) * 1024, ln1b + (l + 1) * 1024, xbuf16, zbuf);
    else
      ln3ln1_kernel<true><<<NM, 256, 0, stream>>>(
          mha, ln3g + 3 * 1024, ln3b + 3 * 1024,
          nullptr, nullptr, d_out, nullptr);
  }
}